// Round 11
// baseline (275.813 us; speedup 1.0000x reference)
//
#include <hip/hip_runtime.h>
#include <hip/hip_bf16.h>
#include <math.h>

#define B_  8
#define N_  1025
#define C_  512
#define H_  8
#define HD_ 64
#define M_  (B_ * N_)   // 8200
#define NCH 33          // ceil(N_/32) key chunks
#define VCS 2048        // shorts per vtc chunk: 64 dims * 32 keys
#define SP  1056        // P row stride (33 chunks * 32), bf16
#define PST 136         // LDS P-tile row stride (shorts): 16B-aligned, 2-way wr

typedef __attribute__((ext_vector_type(8))) short short8;
typedef __attribute__((ext_vector_type(4))) float f32x4;

__device__ inline unsigned short bf16u(float x) {
    __hip_bfloat16 t = __float2bfloat16(x);
    return *(unsigned short*)&t;
}
__device__ inline unsigned pack_bf16x2(float lo, float hi) {
    return ((unsigned)bf16u(hi) << 16) | bf16u(lo);
}
__device__ inline void load_lds16(const void* g, void* l) {
    __builtin_amdgcn_global_load_lds(
        (const __attribute__((address_space(1))) unsigned int*)g,
        (__attribute__((address_space(3))) unsigned int*)l, 16, 0, 0);
}

// ---------------------------------------------------------------------------
// Fused prep: blocks 0..31 build the H x 32 x 32 bias table; rest cast to bf16.
// ---------------------------------------------------------------------------
#define PER_ ((size_t)B_ * H_ * N_ * HD_)      // 4,198,400
#define SZ_QKVW (3 * C_ * C_)
#define SZ_PRJW (C_ * C_)
#define CAST_BLKS ((4198400 + 786432 + 262144) / 4 / 256)   // 5124

__global__ void prep_kernel(const float* __restrict__ x,
                            const float* __restrict__ qkv_w,
                            const float* __restrict__ proj_w,
                            const float* __restrict__ wg_w,
                            const float* __restrict__ wg_b,
                            unsigned short* __restrict__ xb,
                            unsigned short* __restrict__ wqkvb,
                            unsigned short* __restrict__ wprjb,
                            float* __restrict__ tab) {
    int blk = blockIdx.x;
    int tid = threadIdx.x;
    if (blk < 32) {
        int idx = blk * 256 + tid;
        int h = idx >> 10;
        int a = (idx >> 5) & 31;
        int b = idx & 31;
        float dx = logf(fmaxf((float)a * (1.0f / 33.0f), 0.001f));
        float dy = logf(fmaxf((float)b * (1.0f / 33.0f), 0.001f));
        const float* w = wg_w + h * 64;
        float acc = wg_b[h];
#pragma unroll
        for (int k = 0; k < 8; k++) {
            float f = powf(1000.0f, -(float)k * 0.125f);
            float X = 100.0f * dx * f;
            float Y = 100.0f * dy * f;
            acc += w[k]      * sinf(X);
            acc += w[8 + k]  * sinf(Y);
            acc += w[32 + k] * cosf(X);
            acc += w[40 + k] * cosf(Y);
            acc += w[48 + k] + w[56 + k];
        }
        tab[idx] = logf(fmaxf(fmaxf(acc, 0.0f), 1e-6f));
        return;
    }
    long i4 = ((long)(blk - 32) * 256 + tid) * 4;
    const float* src;
    unsigned short* dst;
    long off;
    if (i4 < (long)PER_)                    { src = x;      dst = xb;    off = i4; }
    else if (i4 < (long)PER_ + SZ_QKVW)     { src = qkv_w;  dst = wqkvb; off = i4 - PER_; }
    else                                    { src = proj_w; dst = wprjb; off = i4 - PER_ - SZ_QKVW; }
    float4 v = *(const float4*)(src + off);
    ushort4 p;
    p.x = bf16u(v.x); p.y = bf16u(v.y); p.z = bf16u(v.z); p.w = bf16u(v.w);
    *(ushort4*)(dst + off) = p;
}

// ---------------------------------------------------------------------------
// MFMA GEMM, 128x128 tile, BK=32, 4 waves. q/k swapped-operand -> ushort4
// stores; v scatters to chunked vtc [bh][ch][dim][32].
// ---------------------------------------------------------------------------
#define GK 512

__global__ __launch_bounds__(256) void gemm_qkv_mfma(
        const unsigned short* __restrict__ A, const unsigned short* __restrict__ W,
        unsigned short* __restrict__ qb, unsigned short* __restrict__ kb,
        unsigned short* __restrict__ vtc) {
    __shared__ __align__(16) unsigned short As[128 * 32];
    __shared__ __align__(16) unsigned short Bs[128 * 32];
    int tid = threadIdx.x;
    int w = tid >> 6, lane = tid & 63;
    int quad = lane >> 4, l16 = lane & 15;
    int m0 = blockIdx.y * 128;
    int n0 = blockIdx.x * 128;
    int wr = (w >> 1) * 64, wc = (w & 1) * 64;

    int c0 = tid, c1 = tid + 256;
    int a_r0 = min(m0 + (c0 >> 2), M_ - 1), a_c0 = (c0 & 3) * 8;
    int a_r1 = min(m0 + (c1 >> 2), M_ - 1), a_c1 = (c1 & 3) * 8;
    int b_r0 = n0 + (c0 >> 2), b_r1 = n0 + (c1 >> 2);

    int which = n0 >> 9;                       // 0=q 1=k 2=v
    int h = ((n0 + wc) >> 6) & 7;

    f32x4 acc[4][4];
    const f32x4 zero4 = {0.f, 0.f, 0.f, 0.f};
#pragma unroll
    for (int mi = 0; mi < 4; mi++)
#pragma unroll
        for (int ni = 0; ni < 4; ni++) acc[mi][ni] = zero4;

    if (which < 2) {
        for (int k0 = 0; k0 < GK; k0 += 32) {
            __syncthreads();
            load_lds16(A + (size_t)a_r0 * GK + k0 + a_c0, &As[w * 512]);
            load_lds16(A + (size_t)a_r1 * GK + k0 + a_c1, &As[2048 + w * 512]);
            load_lds16(W + (size_t)b_r0 * GK + k0 + a_c0, &Bs[w * 512]);
            load_lds16(W + (size_t)b_r1 * GK + k0 + a_c1, &Bs[2048 + w * 512]);
            __syncthreads();
            short8 af[4], bf[4];
#pragma unroll
            for (int mi = 0; mi < 4; mi++)
                af[mi] = *(const short8*)&As[(wr + mi * 16 + l16) * 32 + quad * 8];
#pragma unroll
            for (int ni = 0; ni < 4; ni++)
                bf[ni] = *(const short8*)&Bs[(wc + ni * 16 + l16) * 32 + quad * 8];
#pragma unroll
            for (int mi = 0; mi < 4; mi++)
#pragma unroll
                for (int ni = 0; ni < 4; ni++)
                    acc[mi][ni] = __builtin_amdgcn_mfma_f32_16x16x32_bf16(
                        bf[ni], af[mi], acc[mi][ni], 0, 0, 0);
        }
        unsigned short* dst = (which == 0) ? qb : kb;
        float sc = (which == 0) ? 0.125f : 1.0f;
#pragma unroll
        for (int mi = 0; mi < 4; mi++) {
            int m = m0 + wr + mi * 16 + l16;
            if (m < M_) {
                int bb = m / N_;
                int i  = m - bb * N_;
                unsigned short* row = dst + ((size_t)(bb * H_ + h) * N_ + i) * HD_;
#pragma unroll
                for (int ni = 0; ni < 4; ni++) {
                    ushort4 pk;
                    pk.x = bf16u(acc[mi][ni][0] * sc);
                    pk.y = bf16u(acc[mi][ni][1] * sc);
                    pk.z = bf16u(acc[mi][ni][2] * sc);
                    pk.w = bf16u(acc[mi][ni][3] * sc);
                    *(ushort4*)(row + ni * 16 + quad * 4) = pk;
                }
            }
        }
    } else {
        for (int k0 = 0; k0 < GK; k0 += 32) {
            __syncthreads();
            load_lds16(A + (size_t)a_r0 * GK + k0 + a_c0, &As[w * 512]);
            load_lds16(A + (size_t)a_r1 * GK + k0 + a_c1, &As[2048 + w * 512]);
            load_lds16(W + (size_t)b_r0 * GK + k0 + a_c0, &Bs[w * 512]);
            load_lds16(W + (size_t)b_r1 * GK + k0 + a_c1, &Bs[2048 + w * 512]);
            __syncthreads();
            short8 af[4], bf[4];
#pragma unroll
            for (int mi = 0; mi < 4; mi++)
                af[mi] = *(const short8*)&As[(wr + mi * 16 + l16) * 32 + quad * 8];
#pragma unroll
            for (int ni = 0; ni < 4; ni++)
                bf[ni] = *(const short8*)&Bs[(wc + ni * 16 + l16) * 32 + quad * 8];
#pragma unroll
            for (int mi = 0; mi < 4; mi++)
#pragma unroll
                for (int ni = 0; ni < 4; ni++)
                    acc[mi][ni] = __builtin_amdgcn_mfma_f32_16x16x32_bf16(
                        af[mi], bf[ni], acc[mi][ni], 0, 0, 0);
        }
#pragma unroll
        for (int mi = 0; mi < 4; mi++)
#pragma unroll
            for (int reg = 0; reg < 4; reg++) {
                int m = m0 + wr + mi * 16 + quad * 4 + reg;
                if (m < M_) {
                    int bb = m / N_;
                    int i  = m - bb * N_;
                    int ch = i >> 5, key = i & 31;
                    size_t base = ((size_t)(bb * H_ + h) * NCH + ch) * VCS + key;
#pragma unroll
                    for (int ni = 0; ni < 4; ni++)
                        vtc[base + (size_t)(ni * 16 + l16) * 32] = bf16u(acc[mi][ni][reg]);
                }
            }
    }
}

__global__ __launch_bounds__(256) void gemm_proj_mfma(
        const unsigned short* __restrict__ A, const unsigned short* __restrict__ W,
        const float* __restrict__ bias, float* __restrict__ out) {
    __shared__ __align__(16) unsigned short As[128 * 32];
    __shared__ __align__(16) unsigned short Bs[128 * 32];
    int tid = threadIdx.x;
    int w = tid >> 6, lane = tid & 63;
    int quad = lane >> 4, l16 = lane & 15;
    int m0 = blockIdx.y * 128;
    int n0 = blockIdx.x * 128;
    int wr = (w >> 1) * 64, wc = (w & 1) * 64;

    int c0 = tid, c1 = tid + 256;
    int a_r0 = min(m0 + (c0 >> 2), M_ - 1), a_c0 = (c0 & 3) * 8;
    int a_r1 = min(m0 + (c1 >> 2), M_ - 1), a_c1 = (c1 & 3) * 8;
    int b_r0 = n0 + (c0 >> 2), b_r1 = n0 + (c1 >> 2);

    f32x4 acc[4][4];
    const f32x4 zero4 = {0.f, 0.f, 0.f, 0.f};
#pragma unroll
    for (int mi = 0; mi < 4; mi++)
#pragma unroll
        for (int ni = 0; ni < 4; ni++) acc[mi][ni] = zero4;

    for (int k0 = 0; k0 < GK; k0 += 32) {
        __syncthreads();
        load_lds16(A + (size_t)a_r0 * GK + k0 + a_c0, &As[w * 512]);
        load_lds16(A + (size_t)a_r1 * GK + k0 + a_c1, &As[2048 + w * 512]);
        load_lds16(W + (size_t)b_r0 * GK + k0 + a_c0, &Bs[w * 512]);
        load_lds16(W + (size_t)b_r1 * GK + k0 + a_c1, &Bs[2048 + w * 512]);
        __syncthreads();
        short8 af[4], bf[4];
#pragma unroll
        for (int mi = 0; mi < 4; mi++)
            af[mi] = *(const short8*)&As[(wr + mi * 16 + l16) * 32 + quad * 8];
#pragma unroll
        for (int ni = 0; ni < 4; ni++)
            bf[ni] = *(const short8*)&Bs[(wc + ni * 16 + l16) * 32 + quad * 8];
#pragma unroll
        for (int mi = 0; mi < 4; mi++)
#pragma unroll
            for (int ni = 0; ni < 4; ni++)
                acc[mi][ni] = __builtin_amdgcn_mfma_f32_16x16x32_bf16(
                    af[mi], bf[ni], acc[mi][ni], 0, 0, 0);
    }

    float bvals[4];
#pragma unroll
    for (int ni = 0; ni < 4; ni++) bvals[ni] = bias[n0 + wc + ni * 16 + l16];
#pragma unroll
    for (int mi = 0; mi < 4; mi++)
#pragma unroll
        for (int reg = 0; reg < 4; reg++) {
            int m = m0 + wr + mi * 16 + quad * 4 + reg;
            if (m < M_) {
                float* row = out + (size_t)m * C_ + n0 + wc;
#pragma unroll
                for (int ni = 0; ni < 4; ni++)
                    row[ni * 16 + l16] = acc[mi][ni][reg] + bvals[ni];
            }
        }
}

// ---------------------------------------------------------------------------
// Pass 1: P = exp(QK^T + bias). LDS-TRANSPOSE epilogue: pack the 128x128
// P-tile into LDS (stride PST=136: 16B-aligned, 2-way write conflicts),
// barrier, then stream full row-segments with coalesced 16B stores
// (complete 128B lines; no per-lane row scatter).
// ---------------------------------------------------------------------------
__global__ __launch_bounds__(256) void attn_qk_exp(
        const unsigned short* __restrict__ qg,
        const unsigned short* __restrict__ kg,
        const float* __restrict__ tab,
        unsigned short* __restrict__ P) {
    __shared__ __align__(16) unsigned short SH[128 * PST];  // 34816 B
    __shared__ float tabs[34 * 33];                         // 4.5 KB
    unsigned short* Qs = SH;            // 128x64 during compute
    unsigned short* Ks = SH + 8192;     // 128x64 during compute

    int tid = threadIdx.x;
    int w = tid >> 6, lane = tid & 63;
    int quad = lane >> 4, l16 = lane & 15;

    int lin = blockIdx.x;
    int xcd = lin & 7;
    int rest = lin >> 3;
    int bhi = rest & 7;
    int t = rest >> 3;               // 0..80
    int mt = t / 9, nt = t - mt * 9;
    int bh = xcd * 8 + bhi;
    int h = bh & 7;

    const unsigned short* qp = qg + (size_t)bh * N_ * HD_;
    const unsigned short* kp = kg + (size_t)bh * N_ * HD_;

    for (int i = tid; i < 1024; i += 256)
        tabs[(i >> 5) * 33 + (i & 31)] = tab[h * 1024 + i];

#pragma unroll
    for (int r = 0; r < 4; r++) {
        int ch = r * 256 + tid;
        int row = ch >> 3, col8 = (ch & 7) * 8;
        int qr = min(mt * 128 + row, N_ - 1);
        int kr = min(nt * 128 + row, N_ - 1);
        load_lds16(qp + (size_t)qr * HD_ + col8, &Qs[r * 2048 + w * 512]);
        load_lds16(kp + (size_t)kr * HD_ + col8, &Ks[r * 2048 + w * 512]);
    }
    __syncthreads();

    int wr = (w >> 1) * 64, wc = (w & 1) * 64;
    f32x4 acc[4][4];
    const f32x4 zero4 = {0.f, 0.f, 0.f, 0.f};
#pragma unroll
    for (int mi = 0; mi < 4; mi++)
#pragma unroll
        for (int ni = 0; ni < 4; ni++) acc[mi][ni] = zero4;

#pragma unroll
    for (int ks = 0; ks < 2; ks++) {
        short8 af[4], bf[4];
#pragma unroll
        for (int mi = 0; mi < 4; mi++)
            af[mi] = *(const short8*)&Qs[(wr + mi * 16 + l16) * 64 + ks * 32 + quad * 8];
#pragma unroll
        for (int ni = 0; ni < 4; ni++)
            bf[ni] = *(const short8*)&Ks[(wc + ni * 16 + l16) * 64 + ks * 32 + quad * 8];
#pragma unroll
        for (int mi = 0; mi < 4; mi++)
#pragma unroll
            for (int ni = 0; ni < 4; ni++)
                acc[mi][ni] = __builtin_amdgcn_mfma_f32_16x16x32_bf16(
                    bf[ni], af[mi], acc[mi][ni], 0, 0, 0);
    }

    // per (ni,reg) key-col constants
    int jx[4][4], jy[4][4];
    bool jo[4][4], jz[4][4];
#pragma unroll
    for (int ni = 0; ni < 4; ni++)
#pragma unroll
        for (int reg = 0; reg < 4; reg++) {
            int jn = nt * 128 + wc + ni * 16 + quad * 4 + reg;
            int ji = jn - 1;
            jx[ni][reg] = ji >> 5;
            jy[ni][reg] = ji & 31;
            jo[ni][reg] = (jn >= N_);
            jz[ni][reg] = (jn == 0);
        }

    __syncthreads();    // compute done in all waves; SH reusable

    // bias + exp + pack into LDS (local row = wr+mi*16+l16, col = wc+ni*16+quad*4)
#pragma unroll
    for (int mi = 0; mi < 4; mi++) {
        int rowm = mt * 128 + wr + mi * 16 + l16;
        int riv = min(rowm, N_ - 1) - 1;
        int rpx = riv >> 5, rpy = riv & 31;
        bool mz = (rowm == 0);
        unsigned short* dst = &SH[(wr + mi * 16 + l16) * PST];
#pragma unroll
        for (int ni = 0; ni < 4; ni++) {
            float pv[4];
#pragma unroll
            for (int reg = 0; reg < 4; reg++) {
                float bia = 0.f;
                if (!mz && !jz[ni][reg]) {
                    int da = __sad(rpx, jx[ni][reg], 0u);
                    int db = __sad(rpy, jy[ni][reg], 0u);
                    bia = tabs[da * 33 + db];
                }
                float val = __expf(acc[mi][ni][reg] + bia);
                pv[reg] = jo[ni][reg] ? 0.f : val;
            }
            int c0l = wc + ni * 16 + quad * 4;
            *(unsigned*)&dst[c0l]     = pack_bf16x2(pv[0], pv[1]);
            *(unsigned*)&dst[c0l + 2] = pack_bf16x2(pv[2], pv[3]);
        }
    }
    __syncthreads();

    // coalesced store: thread -> (row = tid>>1, half = tid&1), 8 x 16B
    {
        int row = tid >> 1, half = tid & 1;
        int rowm = mt * 128 + row;
        if (rowm < N_) {
            unsigned short* prow = P + (size_t)bh * N_ * SP + (size_t)rowm * SP
                                 + nt * 128 + half * 64;
            const unsigned short* src = &SH[row * PST + half * 64];
            int colg = nt * 128 + half * 64;
#pragma unroll
            for (int j = 0; j < 8; j++) {
                if (colg + j * 8 + 8 <= SP)
                    *(uint4*)(prow + j * 8) = *(const uint4*)(src + j * 8);
            }
        }
    }
}

// ---------------------------------------------------------------------------
// Pass 2: O = P @ V, l = P @ ones; o = O/l -> ob. 512 thr = 8 waves:
// waves 0-3 chunks 0..16, waves 4-7 chunks 17..32 (exact partials, intra-
// block LDS reduction). Depth-4 register prefetch for both P and V.
// ---------------------------------------------------------------------------
__global__ __launch_bounds__(512) void attn_pv(
        const unsigned short* __restrict__ P,
        const unsigned short* __restrict__ vtc,
        unsigned short* __restrict__ ob) {
    __shared__ float Red[4][16][66];    // 16.9 KB: [sub][row][dim0..63 + l@64]

    int tid = threadIdx.x;
    int w = tid >> 6, lane = tid & 63;
    int quad = lane >> 4, l16 = lane & 15;
    int grp = w >> 2, sub = w & 3;

    int lin = blockIdx.x;
    int xcd = lin & 7;
    int rest = lin >> 3;
    int bhi = rest & 7;
    int mt = rest >> 3;              // 0..16
    int bh = xcd * 8 + bhi;
    int b = bh >> 3, h = bh & 7;

    const unsigned short* Pb = P + (size_t)bh * N_ * SP;
    const unsigned short* vp = vtc + (size_t)bh * NCH * VCS;

    int row0 = mt * 64 + sub * 16;
    int rowA = min(row0 + l16, N_ - 1);
    const unsigned short* prow = Pb + (size_t)rowA * SP + quad * 8;

    f32x4 o_acc[4], l_acc;
    const f32x4 zero4 = {0.f, 0.f, 0.f, 0.f};
#pragma unroll
    for (int g2 = 0; g2 < 4; g2++) o_acc[g2] = zero4;
    l_acc = zero4;
    short8 ones;
    {
        short one_bf = (short)0x3F80;
#pragma unroll
        for (int j = 0; j < 8; j++) ones[j] = one_bf;
    }

    auto loadP = [&](int c) -> short8 {
        return *(const short8*)(prow + c * 32);
    };
    auto loadVf = [&](int c, short8* vf) {
        const unsigned short* vc = vp + (size_t)c * VCS + quad * 8;
#pragma unroll
        for (int g2 = 0; g2 < 4; g2++)
            vf[g2] = *(const short8*)(vc + (g2 * 16 + l16) * 32);
    };
    auto compute = [&](const short8& pf, const short8* vf) {
#pragma unroll
        for (int g2 = 0; g2 < 4; g2++)
            o_acc[g2] = __builtin_amdgcn_mfma_f32_16x16x32_bf16(pf, vf[g2], o_acc[g2], 0, 0, 0);
        l_acc = __builtin_amdgcn_mfma_f32_16x16x32_bf16(pf, ones, l_acc, 0, 0, 0);
    };

    int c0 = grp ? 17 : 0;
    int n  = grp ? 16 : 17;

    short8 ps[4];
    short8 vs[4][4];
#pragma unroll
    for (int j = 0; j < 4; j++) { ps[j] = loadP(c0 + j); loadVf(c0 + j, vs[j]); }

#pragma unroll 1
    for (int q = 0; q < 4; q++) {
        int base = c0 + q * 4;
#pragma unroll
        for (int j = 0; j < 4; j++) {
            compute(ps[j], vs[j]);
            int nc = min(base + 4 + j, 32);
            ps[j] = loadP(nc);
            loadVf(nc, vs[j]);
        }
    }
    if (n & 3) compute(ps[0], vs[0]);   // chunk 16 for group 0

    // intra-block reduction: group 1 deposits partials, group 0 combines
    if (grp == 1) {
#pragma unroll
        for (int reg = 0; reg < 4; reg++) {
            int rloc = quad * 4 + reg;
#pragma unroll
            for (int g2 = 0; g2 < 4; g2++)
                Red[sub][rloc][g2 * 16 + l16] = o_acc[g2][reg];
            if (l16 == 0) Red[sub][rloc][64] = l_acc[reg];
        }
    }
    __syncthreads();
    if (grp == 0) {
#pragma unroll
        for (int reg = 0; reg < 4; reg++) {
            int r = row0 + quad * 4 + reg;
            if (r < N_) {
                int rloc = quad * 4 + reg;
                float l = l_acc[reg] + Red[sub][rloc][64];
                float inv = 1.0f / l;
                unsigned short* orow = ob + ((size_t)b * N_ + r) * C_ + h * HD_ + l16;
#pragma unroll
                for (int g2 = 0; g2 < 4; g2++) {
                    float o = o_acc[g2][reg] + Red[sub][rloc][g2 * 16 + l16];
                    orow[g2 * 16] = bf16u(o * inv);
                }
            }
        }
    }
}

// ---------------------------------------------------------------------------
extern "C" void kernel_launch(void* const* d_in, const int* in_sizes, int n_in,
                              void* d_out, int out_size, void* d_ws, size_t ws_size,
                              hipStream_t stream) {
    const float* x      = (const float*)d_in[0];
    const float* qkv_w  = (const float*)d_in[1];
    const float* proj_w = (const float*)d_in[2];
    const float* proj_b = (const float*)d_in[3];
    const float* wg_w   = (const float*)d_in[4];
    const float* wg_b   = (const float*)d_in[5];
    float* out = (float*)d_out;

    const size_t per = PER_;
    char* ws = (char*)d_ws;
    float* tab            = (float*)ws;                           // 32 KB
    unsigned short* xb    = (unsigned short*)(ws + (32 << 10));   // 8,396,800 B
    unsigned short* wqkvb = xb + per;                             // 1,572,864 B
    unsigned short* wprjb = wqkvb + (size_t)SZ_QKVW;              //   524,288 B
    unsigned short* qb    = wprjb + (size_t)SZ_PRJW;              // 8,396,800 B
    unsigned short* kb    = qb + per;                             // 8,396,800 B
    unsigned short* vtc   = kb + per;                             // 8,650,752 B
    unsigned short* ob    = vtc + (size_t)64 * NCH * VCS;         // 8,396,800 B
    unsigned short* P     = ob + per;                             // 138,547,200 B

    prep_kernel<<<32 + CAST_BLKS, 256, 0, stream>>>(x, qkv_w, proj_w, wg_w, wg_b,
                                                    xb, wqkvb, wprjb, tab);
    gemm_qkv_mfma<<<dim3(12, 65), 256, 0, stream>>>(xb, wqkvb, qb, kb, vtc);
    attn_qk_exp<<<8 * 8 * 81, 256, 0, stream>>>(qb, kb, tab, P);
    attn_pv<<<8 * 8 * 17, 512, 0, stream>>>(P, vtc, ob);
    gemm_proj_mfma<<<dim3(4, 65), 256, 0, stream>>>(ob, wprjb, proj_b, out);
}

// Round 12
// 251.585 us; speedup vs baseline: 1.0963x; 1.0963x over previous
//
#include <hip/hip_runtime.h>
#include <hip/hip_bf16.h>
#include <math.h>

#define B_  8
#define N_  1025
#define C_  512
#define H_  8
#define HD_ 64
#define M_  (B_ * N_)   // 8200
#define VCS 2048        // shorts per vtc chunk: 64 dims * 32 keys
#define VST 36          // vtc chunks per bh (33 used + 3 pad for tile 8)

typedef __attribute__((ext_vector_type(8))) short short8;
typedef __attribute__((ext_vector_type(4))) float f32x4;

__device__ inline unsigned short bf16u(float x) {
    __hip_bfloat16 t = __float2bfloat16(x);
    return *(unsigned short*)&t;
}
__device__ inline void load_lds16(const void* g, void* l) {
    __builtin_amdgcn_global_load_lds(
        (const __attribute__((address_space(1))) unsigned int*)g,
        (__attribute__((address_space(3))) unsigned int*)l, 16, 0, 0);
}

// ---------------------------------------------------------------------------
// Fused prep: blocks 0..31 build the H x 32 x 32 bias table; rest cast to bf16.
// ---------------------------------------------------------------------------
#define PER_ ((size_t)B_ * H_ * N_ * HD_)      // 4,198,400
#define SZ_QKVW (3 * C_ * C_)
#define SZ_PRJW (C_ * C_)
#define CAST_BLKS ((4198400 + 786432 + 262144) / 4 / 256)   // 5124

__global__ void prep_kernel(const float* __restrict__ x,
                            const float* __restrict__ qkv_w,
                            const float* __restrict__ proj_w,
                            const float* __restrict__ wg_w,
                            const float* __restrict__ wg_b,
                            unsigned short* __restrict__ xb,
                            unsigned short* __restrict__ wqkvb,
                            unsigned short* __restrict__ wprjb,
                            float* __restrict__ tab) {
    int blk = blockIdx.x;
    int tid = threadIdx.x;
    if (blk < 32) {
        int idx = blk * 256 + tid;
        int h = idx >> 10;
        int a = (idx >> 5) & 31;
        int b = idx & 31;
        float dx = logf(fmaxf((float)a * (1.0f / 33.0f), 0.001f));
        float dy = logf(fmaxf((float)b * (1.0f / 33.0f), 0.001f));
        const float* w = wg_w + h * 64;
        float acc = wg_b[h];
#pragma unroll
        for (int k = 0; k < 8; k++) {
            float f = powf(1000.0f, -(float)k * 0.125f);
            float X = 100.0f * dx * f;
            float Y = 100.0f * dy * f;
            acc += w[k]      * sinf(X);
            acc += w[8 + k]  * sinf(Y);
            acc += w[32 + k] * cosf(X);
            acc += w[40 + k] * cosf(Y);
            acc += w[48 + k] + w[56 + k];
        }
        tab[idx] = logf(fmaxf(fmaxf(acc, 0.0f), 1e-6f));
        return;
    }
    long i4 = ((long)(blk - 32) * 256 + tid) * 4;
    const float* src;
    unsigned short* dst;
    long off;
    if (i4 < (long)PER_)                    { src = x;      dst = xb;    off = i4; }
    else if (i4 < (long)PER_ + SZ_QKVW)     { src = qkv_w;  dst = wqkvb; off = i4 - PER_; }
    else                                    { src = proj_w; dst = wprjb; off = i4 - PER_ - SZ_QKVW; }
    float4 v = *(const float4*)(src + off);
    ushort4 p;
    p.x = bf16u(v.x); p.y = bf16u(v.y); p.z = bf16u(v.z); p.w = bf16u(v.w);
    *(ushort4*)(dst + off) = p;
}

// ---------------------------------------------------------------------------
// MFMA GEMM, 128x128 tile, BK=32, 4 waves. q/k swapped-operand -> ushort4
// stores; v scatters to chunked vtc [bh][ch(VST)][dim][32].
// ---------------------------------------------------------------------------
#define GK 512

__global__ __launch_bounds__(256) void gemm_qkv_mfma(
        const unsigned short* __restrict__ A, const unsigned short* __restrict__ W,
        unsigned short* __restrict__ qb, unsigned short* __restrict__ kb,
        unsigned short* __restrict__ vtc) {
    __shared__ __align__(16) unsigned short As[128 * 32];
    __shared__ __align__(16) unsigned short Bs[128 * 32];
    int tid = threadIdx.x;
    int w = tid >> 6, lane = tid & 63;
    int quad = lane >> 4, l16 = lane & 15;
    int m0 = blockIdx.y * 128;
    int n0 = blockIdx.x * 128;
    int wr = (w >> 1) * 64, wc = (w & 1) * 64;

    int c0 = tid, c1 = tid + 256;
    int a_r0 = min(m0 + (c0 >> 2), M_ - 1), a_c0 = (c0 & 3) * 8;
    int a_r1 = min(m0 + (c1 >> 2), M_ - 1), a_c1 = (c1 & 3) * 8;
    int b_r0 = n0 + (c0 >> 2), b_r1 = n0 + (c1 >> 2);

    int which = n0 >> 9;                       // 0=q 1=k 2=v
    int h = ((n0 + wc) >> 6) & 7;

    f32x4 acc[4][4];
    const f32x4 zero4 = {0.f, 0.f, 0.f, 0.f};
#pragma unroll
    for (int mi = 0; mi < 4; mi++)
#pragma unroll
        for (int ni = 0; ni < 4; ni++) acc[mi][ni] = zero4;

    if (which < 2) {
        for (int k0 = 0; k0 < GK; k0 += 32) {
            __syncthreads();
            load_lds16(A + (size_t)a_r0 * GK + k0 + a_c0, &As[w * 512]);
            load_lds16(A + (size_t)a_r1 * GK + k0 + a_c1, &As[2048 + w * 512]);
            load_lds16(W + (size_t)b_r0 * GK + k0 + a_c0, &Bs[w * 512]);
            load_lds16(W + (size_t)b_r1 * GK + k0 + a_c1, &Bs[2048 + w * 512]);
            __syncthreads();
            short8 af[4], bf[4];
#pragma unroll
            for (int mi = 0; mi < 4; mi++)
                af[mi] = *(const short8*)&As[(wr + mi * 16 + l16) * 32 + quad * 8];
#pragma unroll
            for (int ni = 0; ni < 4; ni++)
                bf[ni] = *(const short8*)&Bs[(wc + ni * 16 + l16) * 32 + quad * 8];
#pragma unroll
            for (int mi = 0; mi < 4; mi++)
#pragma unroll
                for (int ni = 0; ni < 4; ni++)
                    acc[mi][ni] = __builtin_amdgcn_mfma_f32_16x16x32_bf16(
                        bf[ni], af[mi], acc[mi][ni], 0, 0, 0);
        }
        unsigned short* dst = (which == 0) ? qb : kb;
        float sc = (which == 0) ? 0.125f : 1.0f;
#pragma unroll
        for (int mi = 0; mi < 4; mi++) {
            int m = m0 + wr + mi * 16 + l16;
            if (m < M_) {
                int bb = m / N_;
                int i  = m - bb * N_;
                unsigned short* row = dst + ((size_t)(bb * H_ + h) * N_ + i) * HD_;
#pragma unroll
                for (int ni = 0; ni < 4; ni++) {
                    ushort4 pk;
                    pk.x = bf16u(acc[mi][ni][0] * sc);
                    pk.y = bf16u(acc[mi][ni][1] * sc);
                    pk.z = bf16u(acc[mi][ni][2] * sc);
                    pk.w = bf16u(acc[mi][ni][3] * sc);
                    *(ushort4*)(row + ni * 16 + quad * 4) = pk;
                }
            }
        }
    } else {
        for (int k0 = 0; k0 < GK; k0 += 32) {
            __syncthreads();
            load_lds16(A + (size_t)a_r0 * GK + k0 + a_c0, &As[w * 512]);
            load_lds16(A + (size_t)a_r1 * GK + k0 + a_c1, &As[2048 + w * 512]);
            load_lds16(W + (size_t)b_r0 * GK + k0 + a_c0, &Bs[w * 512]);
            load_lds16(W + (size_t)b_r1 * GK + k0 + a_c1, &Bs[2048 + w * 512]);
            __syncthreads();
            short8 af[4], bf[4];
#pragma unroll
            for (int mi = 0; mi < 4; mi++)
                af[mi] = *(const short8*)&As[(wr + mi * 16 + l16) * 32 + quad * 8];
#pragma unroll
            for (int ni = 0; ni < 4; ni++)
                bf[ni] = *(const short8*)&Bs[(wc + ni * 16 + l16) * 32 + quad * 8];
#pragma unroll
            for (int mi = 0; mi < 4; mi++)
#pragma unroll
                for (int ni = 0; ni < 4; ni++)
                    acc[mi][ni] = __builtin_amdgcn_mfma_f32_16x16x32_bf16(
                        af[mi], bf[ni], acc[mi][ni], 0, 0, 0);
        }
#pragma unroll
        for (int mi = 0; mi < 4; mi++)
#pragma unroll
            for (int reg = 0; reg < 4; reg++) {
                int m = m0 + wr + mi * 16 + quad * 4 + reg;
                if (m < M_) {
                    int bb = m / N_;
                    int i  = m - bb * N_;
                    int ch = i >> 5, key = i & 31;
                    size_t base = ((size_t)(bb * H_ + h) * VST + ch) * VCS + key;
#pragma unroll
                    for (int ni = 0; ni < 4; ni++)
                        vtc[base + (size_t)(ni * 16 + l16) * 32] = bf16u(acc[mi][ni][reg]);
                }
            }
    }
}

__global__ __launch_bounds__(256) void gemm_proj_mfma(
        const unsigned short* __restrict__ A, const unsigned short* __restrict__ W,
        const float* __restrict__ bias, float* __restrict__ out) {
    __shared__ __align__(16) unsigned short As[128 * 32];
    __shared__ __align__(16) unsigned short Bs[128 * 32];
    int tid = threadIdx.x;
    int w = tid >> 6, lane = tid & 63;
    int quad = lane >> 4, l16 = lane & 15;
    int m0 = blockIdx.y * 128;
    int n0 = blockIdx.x * 128;
    int wr = (w >> 1) * 64, wc = (w & 1) * 64;

    int c0 = tid, c1 = tid + 256;
    int a_r0 = min(m0 + (c0 >> 2), M_ - 1), a_c0 = (c0 & 3) * 8;
    int a_r1 = min(m0 + (c1 >> 2), M_ - 1), a_c1 = (c1 & 3) * 8;
    int b_r0 = n0 + (c0 >> 2), b_r1 = n0 + (c1 >> 2);

    f32x4 acc[4][4];
    const f32x4 zero4 = {0.f, 0.f, 0.f, 0.f};
#pragma unroll
    for (int mi = 0; mi < 4; mi++)
#pragma unroll
        for (int ni = 0; ni < 4; ni++) acc[mi][ni] = zero4;

    for (int k0 = 0; k0 < GK; k0 += 32) {
        __syncthreads();
        load_lds16(A + (size_t)a_r0 * GK + k0 + a_c0, &As[w * 512]);
        load_lds16(A + (size_t)a_r1 * GK + k0 + a_c1, &As[2048 + w * 512]);
        load_lds16(W + (size_t)b_r0 * GK + k0 + a_c0, &Bs[w * 512]);
        load_lds16(W + (size_t)b_r1 * GK + k0 + a_c1, &Bs[2048 + w * 512]);
        __syncthreads();
        short8 af[4], bf[4];
#pragma unroll
        for (int mi = 0; mi < 4; mi++)
            af[mi] = *(const short8*)&As[(wr + mi * 16 + l16) * 32 + quad * 8];
#pragma unroll
        for (int ni = 0; ni < 4; ni++)
            bf[ni] = *(const short8*)&Bs[(wc + ni * 16 + l16) * 32 + quad * 8];
#pragma unroll
        for (int mi = 0; mi < 4; mi++)
#pragma unroll
            for (int ni = 0; ni < 4; ni++)
                acc[mi][ni] = __builtin_amdgcn_mfma_f32_16x16x32_bf16(
                    af[mi], bf[ni], acc[mi][ni], 0, 0, 0);
    }

    float bvals[4];
#pragma unroll
    for (int ni = 0; ni < 4; ni++) bvals[ni] = bias[n0 + wc + ni * 16 + l16];
#pragma unroll
    for (int mi = 0; mi < 4; mi++)
#pragma unroll
        for (int reg = 0; reg < 4; reg++) {
            int m = m0 + wr + mi * 16 + quad * 4 + reg;
            if (m < M_) {
                float* row = out + (size_t)m * C_ + n0 + wc;
#pragma unroll
                for (int ni = 0; ni < 4; ni++)
                    row[ni * 16 + l16] = acc[mi][ni][reg] + bvals[ni];
            }
        }
}

// ---------------------------------------------------------------------------
// FUSED attention: one block = (bh, 128 q-rows); loops 9 col-tiles of 128
// keys. Per iter: K-tile staged to LDS (double-buffered global_load_lds,
// ONE barrier), 32 QK MFMAs/wave, exp+bias -> per-wave LDS P buffer (no
// barrier), 40 PV MFMAs/wave with V fragments direct from global vtc.
// P never reaches HBM. l via ones-column MFMA; O/l fused in epilogue.
// grid = 576 (8 xcd x 8 bhi x 9 mt), 256 thr. LDS 55.7 KB -> 2 blocks/CU.
// ---------------------------------------------------------------------------
__global__ __launch_bounds__(256) void attn_fused(
        const unsigned short* __restrict__ qg,
        const unsigned short* __restrict__ kg,
        const unsigned short* __restrict__ vtc,
        const float* __restrict__ tab,
        unsigned short* __restrict__ ob) {
    // Ks chunk layout: chunk ch = kt*128 + oct*16 + k16 holds
    // K[key = t*128 + kt*16 + k16][dims oct*8 .. +8]  (16 B each)
    __shared__ __align__(16) unsigned short Ks[2][8192];   // 32 KB
    __shared__ __align__(16) unsigned short Pw[4][32 * 72];// 18 KB, per-wave
    __shared__ float tabs[34 * 33];                        // 4.5 KB

    int tid = threadIdx.x;
    int w = tid >> 6, lane = tid & 63;
    int quad = lane >> 4, l16 = lane & 15;

    int lin = blockIdx.x;
    int xcd = lin & 7;
    int u = lin >> 3;
    int bhi = u & 7;
    int mt = u >> 3;                 // 0..8
    int bh = xcd * 8 + bhi;
    int b = bh >> 3, h = bh & 7;

    const unsigned short* qp = qg + (size_t)bh * N_ * HD_;
    const unsigned short* kp = kg + (size_t)bh * N_ * HD_;
    const unsigned short* vp = vtc + (size_t)bh * VST * VCS;

    for (int i = tid; i < 1024; i += 256)
        tabs[(i >> 5) * 33 + (i & 31)] = tab[h * 1024 + i];

    // Q fragments: wave owns rows mt*128 + w*32 + rt*16 + l16
    short8 qf[2][2];
#pragma unroll
    for (int rt = 0; rt < 2; rt++) {
        int row = min(mt * 128 + w * 32 + rt * 16 + l16, N_ - 1);
        qf[rt][0] = *(const short8*)(qp + (size_t)row * HD_ + quad * 8);
        qf[rt][1] = *(const short8*)(qp + (size_t)row * HD_ + 32 + quad * 8);
    }

    // row-side bias constants (C-layout rows: quad*4+reg)
    int rpx[2][4], rpy[2][4];
    bool rz[2][4];
#pragma unroll
    for (int rt = 0; rt < 2; rt++)
#pragma unroll
        for (int reg = 0; reg < 4; reg++) {
            int r = mt * 128 + w * 32 + rt * 16 + quad * 4 + reg;
            int ri = min(max(r - 1, 0), N_ - 2);
            rpx[rt][reg] = ri >> 5;
            rpy[rt][reg] = ri & 31;
            rz[rt][reg] = (r == 0);
        }

    f32x4 o_acc[2][4], l_acc[2];
    const f32x4 zero4 = {0.f, 0.f, 0.f, 0.f};
#pragma unroll
    for (int rt = 0; rt < 2; rt++) {
#pragma unroll
        for (int g2 = 0; g2 < 4; g2++) o_acc[rt][g2] = zero4;
        l_acc[rt] = zero4;
    }
    short8 ones;
    {
        short one_bf = (short)0x3F80;
#pragma unroll
        for (int j = 0; j < 8; j++) ones[j] = one_bf;
    }

    auto stage = [&](int t, int buf) {
#pragma unroll
        for (int r2 = 0; r2 < 4; r2++) {
            int ch = r2 * 256 + tid;
            int kt = ch >> 7, rem = ch & 127;
            int oct = rem >> 4, k16 = rem & 15;
            int key = min(t * 128 + kt * 16 + k16, N_ - 1);
            load_lds16(kp + (size_t)key * HD_ + oct * 8,
                       &Ks[buf][(r2 * 256 + w * 64) * 8]);
        }
    };

    stage(0, 0);

#pragma unroll 1
    for (int t = 0; t < 9; t++) {
        int buf = t & 1;
        __syncthreads();                  // Ks[buf] ready (vmcnt drained)
        if (t < 8) stage(t + 1, buf ^ 1);

        // ---- QK: S[32 rows][128 cols] = 2rt x 8ct tiles ----
        f32x4 s[2][8];
#pragma unroll
        for (int ct = 0; ct < 8; ct++) {
            short8 b0 = *(const short8*)&Ks[buf][(ct * 128 + (0 * 4 + quad) * 16 + l16) * 8];
            short8 b1 = *(const short8*)&Ks[buf][(ct * 128 + (1 * 4 + quad) * 16 + l16) * 8];
#pragma unroll
            for (int rt = 0; rt < 2; rt++) {
                s[rt][ct] = __builtin_amdgcn_mfma_f32_16x16x32_bf16(qf[rt][0], b0, zero4, 0, 0, 0);
                s[rt][ct] = __builtin_amdgcn_mfma_f32_16x16x32_bf16(qf[rt][1], b1, s[rt][ct], 0, 0, 0);
            }
        }

        // ---- two col-halves: exp+pack (per-wave LDS), then PV ----
#pragma unroll
        for (int hh = 0; hh < 2; hh++) {
#pragma unroll
            for (int ct2 = 0; ct2 < 4; ct2++) {
                int ct = hh * 4 + ct2;
                int col = t * 128 + ct * 16 + l16;
                int ji = col - 1;
                int cx = ji >> 5, cy = ji & 31;
                bool cz = (col == 0), co = (col >= N_);
#pragma unroll
                for (int rt = 0; rt < 2; rt++)
#pragma unroll
                    for (int reg = 0; reg < 4; reg++) {
                        float bia = 0.f;
                        if (!rz[rt][reg] && !cz) {
                            int da = __sad(rpx[rt][reg], cx, 0u);
                            int db = __sad(rpy[rt][reg], cy, 0u);
                            bia = tabs[da * 33 + db];
                        }
                        float p = co ? 0.f : __expf(s[rt][ct][reg] + bia);
                        Pw[w][(rt * 16 + quad * 4 + reg) * 72 + ct2 * 16 + l16] = bf16u(p);
                    }
            }
            // PV for this 64-key half (2 k-steps of 32)
#pragma unroll
            for (int ks = 0; ks < 2; ks++) {
                int vc = t * 4 + hh * 2 + ks;
                short8 pf[2];
#pragma unroll
                for (int rt = 0; rt < 2; rt++)
                    pf[rt] = *(const short8*)&Pw[w][(rt * 16 + l16) * 72 + ks * 32 + quad * 8];
                const unsigned short* vcp = vp + (size_t)vc * VCS + quad * 8;
#pragma unroll
                for (int g2 = 0; g2 < 4; g2++) {
                    short8 vf = *(const short8*)(vcp + (g2 * 16 + l16) * 32);
#pragma unroll
                    for (int rt = 0; rt < 2; rt++)
                        o_acc[rt][g2] = __builtin_amdgcn_mfma_f32_16x16x32_bf16(
                            pf[rt], vf, o_acc[rt][g2], 0, 0, 0);
                }
#pragma unroll
                for (int rt = 0; rt < 2; rt++)
                    l_acc[rt] = __builtin_amdgcn_mfma_f32_16x16x32_bf16(
                        pf[rt], ones, l_acc[rt], 0, 0, 0);
            }
        }
    }

    // ---- epilogue: o/l -> ob bf16 (C-layout rows) ----
#pragma unroll
    for (int rt = 0; rt < 2; rt++)
#pragma unroll
        for (int reg = 0; reg < 4; reg++) {
            int r = mt * 128 + w * 32 + rt * 16 + quad * 4 + reg;
            if (r < N_) {
                float inv = 1.0f / l_acc[rt][reg];
                unsigned short* orow = ob + ((size_t)b * N_ + r) * C_ + h * HD_ + l16;
#pragma unroll
                for (int g2 = 0; g2 < 4; g2++)
                    orow[g2 * 16] = bf16u(o_acc[rt][g2][reg] * inv);
            }
        }
}

// ---------------------------------------------------------------------------
extern "C" void kernel_launch(void* const* d_in, const int* in_sizes, int n_in,
                              void* d_out, int out_size, void* d_ws, size_t ws_size,
                              hipStream_t stream) {
    const float* x      = (const float*)d_in[0];
    const float* qkv_w  = (const float*)d_in[1];
    const float* proj_w = (const float*)d_in[2];
    const float* proj_b = (const float*)d_in[3];
    const float* wg_w   = (const float*)d_in[4];
    const float* wg_b   = (const float*)d_in[5];
    float* out = (float*)d_out;

    const size_t per = PER_;
    char* ws = (char*)d_ws;
    float* tab            = (float*)ws;                           // 32 KB
    unsigned short* xb    = (unsigned short*)(ws + (32 << 10));   // 8,396,800 B
    unsigned short* wqkvb = xb + per;                             // 1,572,864 B
    unsigned short* wprjb = wqkvb + (size_t)SZ_QKVW;              //   524,288 B
    unsigned short* qb    = wprjb + (size_t)SZ_PRJW;              // 8,396,800 B
    unsigned short* kb    = qb + per;                             // 8,396,800 B
    unsigned short* vtc   = kb + per;                             // 64*36*2048*2 = 9,437,184 B
    unsigned short* ob    = vtc + (size_t)64 * VST * VCS;         // 8,396,800 B

    prep_kernel<<<32 + CAST_BLKS, 256, 0, stream>>>(x, qkv_w, proj_w, wg_w, wg_b,
                                                    xb, wqkvb, wprjb, tab);
    gemm_qkv_mfma<<<dim3(12, 65), 256, 0, stream>>>(xb, wqkvb, qb, kb, vtc);
    attn_fused<<<8 * 8 * 9, 256, 0, stream>>>(qb, kb, vtc, tab, ob);
    gemm_proj_mfma<<<dim3(4, 65), 256, 0, stream>>>(ob, wprjb, proj_b, out);
}

// Round 13
// 229.975 us; speedup vs baseline: 1.1993x; 1.0940x over previous
//
#include <hip/hip_runtime.h>
#include <hip/hip_bf16.h>
#include <math.h>

#define B_  8
#define N_  1025
#define C_  512
#define H_  8
#define HD_ 64
#define M_  (B_ * N_)   // 8200
#define VCS 2048        // shorts per vtc chunk: 64 dims * 32 keys
#define VST 36          // vtc chunks per bh (33 used + 3 pad for tile 8)

typedef __attribute__((ext_vector_type(8))) short short8;
typedef __attribute__((ext_vector_type(4))) float f32x4;

__device__ inline unsigned short bf16u(float x) {
    __hip_bfloat16 t = __float2bfloat16(x);
    return *(unsigned short*)&t;
}
__device__ inline void load_lds16(const void* g, void* l) {
    __builtin_amdgcn_global_load_lds(
        (const __attribute__((address_space(1))) unsigned int*)g,
        (__attribute__((address_space(3))) unsigned int*)l, 16, 0, 0);
}

// ---------------------------------------------------------------------------
// Fused prep: blocks 0..31 build the H x 32 x 32 bias table; rest cast to bf16.
// ---------------------------------------------------------------------------
#define PER_ ((size_t)B_ * H_ * N_ * HD_)      // 4,198,400
#define SZ_QKVW (3 * C_ * C_)
#define SZ_PRJW (C_ * C_)
#define CAST_BLKS ((4198400 + 786432 + 262144) / 4 / 256)   // 5124

__global__ void prep_kernel(const float* __restrict__ x,
                            const float* __restrict__ qkv_w,
                            const float* __restrict__ proj_w,
                            const float* __restrict__ wg_w,
                            const float* __restrict__ wg_b,
                            unsigned short* __restrict__ xb,
                            unsigned short* __restrict__ wqkvb,
                            unsigned short* __restrict__ wprjb,
                            float* __restrict__ tab) {
    int blk = blockIdx.x;
    int tid = threadIdx.x;
    if (blk < 32) {
        int idx = blk * 256 + tid;
        int h = idx >> 10;
        int a = (idx >> 5) & 31;
        int b = idx & 31;
        float dx = logf(fmaxf((float)a * (1.0f / 33.0f), 0.001f));
        float dy = logf(fmaxf((float)b * (1.0f / 33.0f), 0.001f));
        const float* w = wg_w + h * 64;
        float acc = wg_b[h];
#pragma unroll
        for (int k = 0; k < 8; k++) {
            float f = powf(1000.0f, -(float)k * 0.125f);
            float X = 100.0f * dx * f;
            float Y = 100.0f * dy * f;
            acc += w[k]      * sinf(X);
            acc += w[8 + k]  * sinf(Y);
            acc += w[32 + k] * cosf(X);
            acc += w[40 + k] * cosf(Y);
            acc += w[48 + k] + w[56 + k];
        }
        tab[idx] = logf(fmaxf(fmaxf(acc, 0.0f), 1e-6f));
        return;
    }
    long i4 = ((long)(blk - 32) * 256 + tid) * 4;
    const float* src;
    unsigned short* dst;
    long off;
    if (i4 < (long)PER_)                    { src = x;      dst = xb;    off = i4; }
    else if (i4 < (long)PER_ + SZ_QKVW)     { src = qkv_w;  dst = wqkvb; off = i4 - PER_; }
    else                                    { src = proj_w; dst = wprjb; off = i4 - PER_ - SZ_QKVW; }
    float4 v = *(const float4*)(src + off);
    ushort4 p;
    p.x = bf16u(v.x); p.y = bf16u(v.y); p.z = bf16u(v.z); p.w = bf16u(v.w);
    *(ushort4*)(dst + off) = p;
}

// ---------------------------------------------------------------------------
// MFMA GEMM, 128x128 tile, BK=32, 4 waves. q/k swapped-operand -> ushort4
// stores; v scatters to chunked vtc [bh][ch(VST)][dim][32].
// ---------------------------------------------------------------------------
#define GK 512

__global__ __launch_bounds__(256) void gemm_qkv_mfma(
        const unsigned short* __restrict__ A, const unsigned short* __restrict__ W,
        unsigned short* __restrict__ qb, unsigned short* __restrict__ kb,
        unsigned short* __restrict__ vtc) {
    __shared__ __align__(16) unsigned short As[128 * 32];
    __shared__ __align__(16) unsigned short Bs[128 * 32];
    int tid = threadIdx.x;
    int w = tid >> 6, lane = tid & 63;
    int quad = lane >> 4, l16 = lane & 15;
    int m0 = blockIdx.y * 128;
    int n0 = blockIdx.x * 128;
    int wr = (w >> 1) * 64, wc = (w & 1) * 64;

    int c0 = tid, c1 = tid + 256;
    int a_r0 = min(m0 + (c0 >> 2), M_ - 1), a_c0 = (c0 & 3) * 8;
    int a_r1 = min(m0 + (c1 >> 2), M_ - 1), a_c1 = (c1 & 3) * 8;
    int b_r0 = n0 + (c0 >> 2), b_r1 = n0 + (c1 >> 2);

    int which = n0 >> 9;                       // 0=q 1=k 2=v
    int h = ((n0 + wc) >> 6) & 7;

    f32x4 acc[4][4];
    const f32x4 zero4 = {0.f, 0.f, 0.f, 0.f};
#pragma unroll
    for (int mi = 0; mi < 4; mi++)
#pragma unroll
        for (int ni = 0; ni < 4; ni++) acc[mi][ni] = zero4;

    if (which < 2) {
        for (int k0 = 0; k0 < GK; k0 += 32) {
            __syncthreads();
            load_lds16(A + (size_t)a_r0 * GK + k0 + a_c0, &As[w * 512]);
            load_lds16(A + (size_t)a_r1 * GK + k0 + a_c1, &As[2048 + w * 512]);
            load_lds16(W + (size_t)b_r0 * GK + k0 + a_c0, &Bs[w * 512]);
            load_lds16(W + (size_t)b_r1 * GK + k0 + a_c1, &Bs[2048 + w * 512]);
            __syncthreads();
            short8 af[4], bf[4];
#pragma unroll
            for (int mi = 0; mi < 4; mi++)
                af[mi] = *(const short8*)&As[(wr + mi * 16 + l16) * 32 + quad * 8];
#pragma unroll
            for (int ni = 0; ni < 4; ni++)
                bf[ni] = *(const short8*)&Bs[(wc + ni * 16 + l16) * 32 + quad * 8];
#pragma unroll
            for (int mi = 0; mi < 4; mi++)
#pragma unroll
                for (int ni = 0; ni < 4; ni++)
                    acc[mi][ni] = __builtin_amdgcn_mfma_f32_16x16x32_bf16(
                        bf[ni], af[mi], acc[mi][ni], 0, 0, 0);
        }
        unsigned short* dst = (which == 0) ? qb : kb;
        float sc = (which == 0) ? 0.125f : 1.0f;
#pragma unroll
        for (int mi = 0; mi < 4; mi++) {
            int m = m0 + wr + mi * 16 + l16;
            if (m < M_) {
                int bb = m / N_;
                int i  = m - bb * N_;
                unsigned short* row = dst + ((size_t)(bb * H_ + h) * N_ + i) * HD_;
#pragma unroll
                for (int ni = 0; ni < 4; ni++) {
                    ushort4 pk;
                    pk.x = bf16u(acc[mi][ni][0] * sc);
                    pk.y = bf16u(acc[mi][ni][1] * sc);
                    pk.z = bf16u(acc[mi][ni][2] * sc);
                    pk.w = bf16u(acc[mi][ni][3] * sc);
                    *(ushort4*)(row + ni * 16 + quad * 4) = pk;
                }
            }
        }
    } else {
        for (int k0 = 0; k0 < GK; k0 += 32) {
            __syncthreads();
            load_lds16(A + (size_t)a_r0 * GK + k0 + a_c0, &As[w * 512]);
            load_lds16(A + (size_t)a_r1 * GK + k0 + a_c1, &As[2048 + w * 512]);
            load_lds16(W + (size_t)b_r0 * GK + k0 + a_c0, &Bs[w * 512]);
            load_lds16(W + (size_t)b_r1 * GK + k0 + a_c1, &Bs[2048 + w * 512]);
            __syncthreads();
            short8 af[4], bf[4];
#pragma unroll
            for (int mi = 0; mi < 4; mi++)
                af[mi] = *(const short8*)&As[(wr + mi * 16 + l16) * 32 + quad * 8];
#pragma unroll
            for (int ni = 0; ni < 4; ni++)
                bf[ni] = *(const short8*)&Bs[(wc + ni * 16 + l16) * 32 + quad * 8];
#pragma unroll
            for (int mi = 0; mi < 4; mi++)
#pragma unroll
                for (int ni = 0; ni < 4; ni++)
                    acc[mi][ni] = __builtin_amdgcn_mfma_f32_16x16x32_bf16(
                        af[mi], bf[ni], acc[mi][ni], 0, 0, 0);
        }
#pragma unroll
        for (int mi = 0; mi < 4; mi++)
#pragma unroll
            for (int reg = 0; reg < 4; reg++) {
                int m = m0 + wr + mi * 16 + quad * 4 + reg;
                if (m < M_) {
                    int bb = m / N_;
                    int i  = m - bb * N_;
                    int ch = i >> 5, key = i & 31;
                    size_t base = ((size_t)(bb * H_ + h) * VST + ch) * VCS + key;
#pragma unroll
                    for (int ni = 0; ni < 4; ni++)
                        vtc[base + (size_t)(ni * 16 + l16) * 32] = bf16u(acc[mi][ni][reg]);
                }
            }
    }
}

__global__ __launch_bounds__(256) void gemm_proj_mfma(
        const unsigned short* __restrict__ A, const unsigned short* __restrict__ W,
        const float* __restrict__ bias, float* __restrict__ out) {
    __shared__ __align__(16) unsigned short As[128 * 32];
    __shared__ __align__(16) unsigned short Bs[128 * 32];
    int tid = threadIdx.x;
    int w = tid >> 6, lane = tid & 63;
    int quad = lane >> 4, l16 = lane & 15;
    int m0 = blockIdx.y * 128;
    int n0 = blockIdx.x * 128;
    int wr = (w >> 1) * 64, wc = (w & 1) * 64;

    int c0 = tid, c1 = tid + 256;
    int a_r0 = min(m0 + (c0 >> 2), M_ - 1), a_c0 = (c0 & 3) * 8;
    int a_r1 = min(m0 + (c1 >> 2), M_ - 1), a_c1 = (c1 & 3) * 8;
    int b_r0 = n0 + (c0 >> 2), b_r1 = n0 + (c1 >> 2);

    f32x4 acc[4][4];
    const f32x4 zero4 = {0.f, 0.f, 0.f, 0.f};
#pragma unroll
    for (int mi = 0; mi < 4; mi++)
#pragma unroll
        for (int ni = 0; ni < 4; ni++) acc[mi][ni] = zero4;

    for (int k0 = 0; k0 < GK; k0 += 32) {
        __syncthreads();
        load_lds16(A + (size_t)a_r0 * GK + k0 + a_c0, &As[w * 512]);
        load_lds16(A + (size_t)a_r1 * GK + k0 + a_c1, &As[2048 + w * 512]);
        load_lds16(W + (size_t)b_r0 * GK + k0 + a_c0, &Bs[w * 512]);
        load_lds16(W + (size_t)b_r1 * GK + k0 + a_c1, &Bs[2048 + w * 512]);
        __syncthreads();
        short8 af[4], bf[4];
#pragma unroll
        for (int mi = 0; mi < 4; mi++)
            af[mi] = *(const short8*)&As[(wr + mi * 16 + l16) * 32 + quad * 8];
#pragma unroll
        for (int ni = 0; ni < 4; ni++)
            bf[ni] = *(const short8*)&Bs[(wc + ni * 16 + l16) * 32 + quad * 8];
#pragma unroll
        for (int mi = 0; mi < 4; mi++)
#pragma unroll
            for (int ni = 0; ni < 4; ni++)
                acc[mi][ni] = __builtin_amdgcn_mfma_f32_16x16x32_bf16(
                    af[mi], bf[ni], acc[mi][ni], 0, 0, 0);
    }

    float bvals[4];
#pragma unroll
    for (int ni = 0; ni < 4; ni++) bvals[ni] = bias[n0 + wc + ni * 16 + l16];
#pragma unroll
    for (int mi = 0; mi < 4; mi++)
#pragma unroll
        for (int reg = 0; reg < 4; reg++) {
            int m = m0 + wr + mi * 16 + quad * 4 + reg;
            if (m < M_) {
                float* row = out + (size_t)m * C_ + n0 + wc;
#pragma unroll
                for (int ni = 0; ni < 4; ni++)
                    row[ni * 16 + l16] = acc[mi][ni][reg] + bvals[ni];
            }
        }
}

// ---------------------------------------------------------------------------
// FUSED attention, 8-WAVE blocks: one block = (bh, 128 q-rows), each wave
// owns 16 rows. Loops 9 col-tiles of 128 keys: K-tile staged to LDS
// (double-buffered global_load_lds, ONE barrier/iter), 16 QK MFMAs/wave,
// exp+bias -> per-wave LDS P buffer (no barrier), 20 PV MFMAs/wave with V
// direct from global vtc. P never reaches HBM. LDS ~55 KB -> 2 blocks/CU
// x 8 waves = 16 waves/CU (R12's 4-wave block gave only 8 waves/CU).
// ---------------------------------------------------------------------------
__global__ __launch_bounds__(512) void attn_fused(
        const unsigned short* __restrict__ qg,
        const unsigned short* __restrict__ kg,
        const unsigned short* __restrict__ vtc,
        const float* __restrict__ tab,
        unsigned short* __restrict__ ob) {
    // Ks chunk layout: chunk ch = ct*128 + oct*16 + k16 holds
    // K[key = t*128 + ct*16 + k16][dims oct*8 .. +8]  (16 B each)
    __shared__ __align__(16) unsigned short Ks[2][8192];   // 32 KB
    __shared__ __align__(16) unsigned short Pw[8][16 * 72];// 18 KB, per-wave
    __shared__ float tabs[34 * 33];                        // 4.5 KB

    int tid = threadIdx.x;
    int w = tid >> 6, lane = tid & 63;
    int quad = lane >> 4, l16 = lane & 15;

    int lin = blockIdx.x;
    int xcd = lin & 7;
    int u = lin >> 3;
    int bhi = u & 7;
    int mt = u >> 3;                 // 0..8
    int bh = xcd * 8 + bhi;
    int b = bh >> 3, h = bh & 7;

    const unsigned short* qp = qg + (size_t)bh * N_ * HD_;
    const unsigned short* kp = kg + (size_t)bh * N_ * HD_;
    const unsigned short* vp = vtc + (size_t)bh * VST * VCS;

    for (int i = tid; i < 1024; i += 512)
        tabs[(i >> 5) * 33 + (i & 31)] = tab[h * 1024 + i];

    // Q fragments: wave owns rows mt*128 + w*16 + l16 (A-layout)
    short8 qf[2];
    {
        int row = min(mt * 128 + w * 16 + l16, N_ - 1);
        qf[0] = *(const short8*)(qp + (size_t)row * HD_ + quad * 8);
        qf[1] = *(const short8*)(qp + (size_t)row * HD_ + 32 + quad * 8);
    }

    // row-side bias constants (C-layout rows: quad*4+reg)
    int rpx[4], rpy[4];
    bool rz[4];
#pragma unroll
    for (int reg = 0; reg < 4; reg++) {
        int r = mt * 128 + w * 16 + quad * 4 + reg;
        int ri = min(max(r - 1, 0), N_ - 2);
        rpx[reg] = ri >> 5;
        rpy[reg] = ri & 31;
        rz[reg] = (r == 0);
    }

    f32x4 o_acc[4], l_acc;
    const f32x4 zero4 = {0.f, 0.f, 0.f, 0.f};
#pragma unroll
    for (int g2 = 0; g2 < 4; g2++) o_acc[g2] = zero4;
    l_acc = zero4;
    short8 ones;
    {
        short one_bf = (short)0x3F80;
#pragma unroll
        for (int j = 0; j < 8; j++) ones[j] = one_bf;
    }

    auto stage = [&](int t, int buf) {
#pragma unroll
        for (int r2 = 0; r2 < 2; r2++) {
            int ch = r2 * 512 + tid;
            int ct = ch >> 7, rem = ch & 127;
            int oct = rem >> 4, k16 = rem & 15;
            int key = min(t * 128 + ct * 16 + k16, N_ - 1);
            load_lds16(kp + (size_t)key * HD_ + oct * 8,
                       &Ks[buf][(r2 * 512 + w * 64) * 8]);
        }
    };

    stage(0, 0);

#pragma unroll 1
    for (int t = 0; t < 9; t++) {
        int buf = t & 1;
        __syncthreads();                  // Ks[buf] ready (vmcnt drained)
        if (t < 8) stage(t + 1, buf ^ 1);

        // ---- QK: S[16 rows][128 cols] = 8 ct tiles ----
        f32x4 s[8];
#pragma unroll
        for (int ct = 0; ct < 8; ct++) {
            short8 b0 = *(const short8*)&Ks[buf][(ct * 128 + quad * 16 + l16) * 8];
            short8 b1 = *(const short8*)&Ks[buf][(ct * 128 + (4 + quad) * 16 + l16) * 8];
            s[ct] = __builtin_amdgcn_mfma_f32_16x16x32_bf16(qf[0], b0, zero4, 0, 0, 0);
            s[ct] = __builtin_amdgcn_mfma_f32_16x16x32_bf16(qf[1], b1, s[ct], 0, 0, 0);
        }

        // ---- two col-halves: exp+pack (per-wave LDS), then PV ----
#pragma unroll
        for (int hh = 0; hh < 2; hh++) {
#pragma unroll
            for (int ct2 = 0; ct2 < 4; ct2++) {
                int ct = hh * 4 + ct2;
                int col = t * 128 + ct * 16 + l16;
                int ji = col - 1;
                int cx = ji >> 5, cy = ji & 31;
                bool cz = (col == 0), co = (col >= N_);
#pragma unroll
                for (int reg = 0; reg < 4; reg++) {
                    float bia = 0.f;
                    if (!rz[reg] && !cz) {
                        int da = __sad(rpx[reg], cx, 0u);
                        int db = __sad(rpy[reg], cy, 0u);
                        bia = tabs[da * 33 + db];
                    }
                    float p = co ? 0.f : __expf(s[ct][reg] + bia);
                    Pw[w][(quad * 4 + reg) * 72 + ct2 * 16 + l16] = bf16u(p);
                }
            }
            // PV for this 64-key half (2 k-steps of 32)
#pragma unroll
            for (int ks = 0; ks < 2; ks++) {
                int vc = t * 4 + hh * 2 + ks;
                short8 pf = *(const short8*)&Pw[w][l16 * 72 + ks * 32 + quad * 8];
                const unsigned short* vcp = vp + (size_t)vc * VCS + quad * 8;
#pragma unroll
                for (int g2 = 0; g2 < 4; g2++) {
                    short8 vf = *(const short8*)(vcp + (g2 * 16 + l16) * 32);
                    o_acc[g2] = __builtin_amdgcn_mfma_f32_16x16x32_bf16(
                        pf, vf, o_acc[g2], 0, 0, 0);
                }
                l_acc = __builtin_amdgcn_mfma_f32_16x16x32_bf16(pf, ones, l_acc, 0, 0, 0);
            }
        }
    }

    // ---- epilogue: o/l -> ob bf16 (C-layout rows) ----
#pragma unroll
    for (int reg = 0; reg < 4; reg++) {
        int r = mt * 128 + w * 16 + quad * 4 + reg;
        if (r < N_) {
            float inv = 1.0f / l_acc[reg];
            unsigned short* orow = ob + ((size_t)b * N_ + r) * C_ + h * HD_ + l16;
#pragma unroll
            for (int g2 = 0; g2 < 4; g2++)
                orow[g2 * 16] = bf16u(o_acc[g2][reg] * inv);
        }
    }
}

// ---------------------------------------------------------------------------
extern "C" void kernel_launch(void* const* d_in, const int* in_sizes, int n_in,
                              void* d_out, int out_size, void* d_ws, size_t ws_size,
                              hipStream_t stream) {
    const float* x      = (const float*)d_in[0];
    const float* qkv_w  = (const float*)d_in[1];
    const float* proj_w = (const float*)d_in[2];
    const float* proj_b = (const float*)d_in[3];
    const float* wg_w   = (const float*)d_in[4];
    const float* wg_b   = (const float*)d_in[5];
    float* out = (float*)d_out;

    const size_t per = PER_;
    char* ws = (char*)d_ws;
    float* tab            = (float*)ws;                           // 32 KB
    unsigned short* xb    = (unsigned short*)(ws + (32 << 10));   // 8,396,800 B
    unsigned short* wqkvb = xb + per;                             // 1,572,864 B
    unsigned short* wprjb = wqkvb + (size_t)SZ_QKVW;              //   524,288 B
    unsigned short* qb    = wprjb + (size_t)SZ_PRJW;              // 8,396,800 B
    unsigned short* kb    = qb + per;                             // 8,396,800 B
    unsigned short* vtc   = kb + per;                             // 9,437,184 B
    unsigned short* ob    = vtc + (size_t)64 * VST * VCS;         // 8,396,800 B

    prep_kernel<<<32 + CAST_BLKS, 256, 0, stream>>>(x, qkv_w, proj_w, wg_w, wg_b,
                                                    xb, wqkvb, wprjb, tab);
    gemm_qkv_mfma<<<dim3(12, 65), 256, 0, stream>>>(xb, wqkvb, qb, kb, vtc);
    attn_fused<<<8 * 8 * 9, 512, 0, stream>>>(qb, kb, vtc, tab, ob);
    gemm_proj_mfma<<<dim3(4, 65), 256, 0, stream>>>(ob, wprjb, proj_b, out);
}

// Round 14
// 228.201 us; speedup vs baseline: 1.2086x; 1.0078x over previous
//
#include <hip/hip_runtime.h>
#include <hip/hip_bf16.h>
#include <math.h>

#define B_  8
#define N_  1025
#define C_  512
#define H_  8
#define HD_ 64
#define M_  (B_ * N_)   // 8200
#define VCS 2048        // shorts per vtc chunk: 64 dims * 32 keys
#define VST 36          // vtc chunks per bh (33 used + 3 pad for tile 8)

typedef __attribute__((ext_vector_type(8))) short short8;
typedef __attribute__((ext_vector_type(4))) float f32x4;

__device__ inline unsigned short bf16u(float x) {
    __hip_bfloat16 t = __float2bfloat16(x);
    return *(unsigned short*)&t;
}
__device__ inline void load_lds16(const void* g, void* l) {
    __builtin_amdgcn_global_load_lds(
        (const __attribute__((address_space(1))) unsigned int*)g,
        (__attribute__((address_space(3))) unsigned int*)l, 16, 0, 0);
}

// ---------------------------------------------------------------------------
// Fused prep: blocks 0..31 build the H x 32 x 32 bias table; rest cast to bf16.
// ---------------------------------------------------------------------------
#define PER_ ((size_t)B_ * H_ * N_ * HD_)      // 4,198,400
#define SZ_QKVW (3 * C_ * C_)
#define SZ_PRJW (C_ * C_)
#define CAST_BLKS ((4198400 + 786432 + 262144) / 4 / 256)   // 5124

__global__ void prep_kernel(const float* __restrict__ x,
                            const float* __restrict__ qkv_w,
                            const float* __restrict__ proj_w,
                            const float* __restrict__ wg_w,
                            const float* __restrict__ wg_b,
                            unsigned short* __restrict__ xb,
                            unsigned short* __restrict__ wqkvb,
                            unsigned short* __restrict__ wprjb,
                            float* __restrict__ tab) {
    int blk = blockIdx.x;
    int tid = threadIdx.x;
    if (blk < 32) {
        int idx = blk * 256 + tid;
        int h = idx >> 10;
        int a = (idx >> 5) & 31;
        int b = idx & 31;
        float dx = logf(fmaxf((float)a * (1.0f / 33.0f), 0.001f));
        float dy = logf(fmaxf((float)b * (1.0f / 33.0f), 0.001f));
        const float* w = wg_w + h * 64;
        float acc = wg_b[h];
#pragma unroll
        for (int k = 0; k < 8; k++) {
            float f = powf(1000.0f, -(float)k * 0.125f);
            float X = 100.0f * dx * f;
            float Y = 100.0f * dy * f;
            acc += w[k]      * sinf(X);
            acc += w[8 + k]  * sinf(Y);
            acc += w[32 + k] * cosf(X);
            acc += w[40 + k] * cosf(Y);
            acc += w[48 + k] + w[56 + k];
        }
        tab[idx] = logf(fmaxf(fmaxf(acc, 0.0f), 1e-6f));
        return;
    }
    long i4 = ((long)(blk - 32) * 256 + tid) * 4;
    const float* src;
    unsigned short* dst;
    long off;
    if (i4 < (long)PER_)                    { src = x;      dst = xb;    off = i4; }
    else if (i4 < (long)PER_ + SZ_QKVW)     { src = qkv_w;  dst = wqkvb; off = i4 - PER_; }
    else                                    { src = proj_w; dst = wprjb; off = i4 - PER_ - SZ_QKVW; }
    float4 v = *(const float4*)(src + off);
    ushort4 p;
    p.x = bf16u(v.x); p.y = bf16u(v.y); p.z = bf16u(v.z); p.w = bf16u(v.w);
    *(ushort4*)(dst + off) = p;
}

// ---------------------------------------------------------------------------
// MFMA GEMM, 128x128 tile, BK=32, 4 waves. q/k swapped-operand -> ushort4
// stores; v scatters to chunked vtc [bh][ch(VST)][dim][32].
// ---------------------------------------------------------------------------
#define GK 512

__global__ __launch_bounds__(256) void gemm_qkv_mfma(
        const unsigned short* __restrict__ A, const unsigned short* __restrict__ W,
        unsigned short* __restrict__ qb, unsigned short* __restrict__ kb,
        unsigned short* __restrict__ vtc) {
    __shared__ __align__(16) unsigned short As[128 * 32];
    __shared__ __align__(16) unsigned short Bs[128 * 32];
    int tid = threadIdx.x;
    int w = tid >> 6, lane = tid & 63;
    int quad = lane >> 4, l16 = lane & 15;
    int m0 = blockIdx.y * 128;
    int n0 = blockIdx.x * 128;
    int wr = (w >> 1) * 64, wc = (w & 1) * 64;

    int c0 = tid, c1 = tid + 256;
    int a_r0 = min(m0 + (c0 >> 2), M_ - 1), a_c0 = (c0 & 3) * 8;
    int a_r1 = min(m0 + (c1 >> 2), M_ - 1), a_c1 = (c1 & 3) * 8;
    int b_r0 = n0 + (c0 >> 2), b_r1 = n0 + (c1 >> 2);

    int which = n0 >> 9;                       // 0=q 1=k 2=v
    int h = ((n0 + wc) >> 6) & 7;

    f32x4 acc[4][4];
    const f32x4 zero4 = {0.f, 0.f, 0.f, 0.f};
#pragma unroll
    for (int mi = 0; mi < 4; mi++)
#pragma unroll
        for (int ni = 0; ni < 4; ni++) acc[mi][ni] = zero4;

    if (which < 2) {
        for (int k0 = 0; k0 < GK; k0 += 32) {
            __syncthreads();
            load_lds16(A + (size_t)a_r0 * GK + k0 + a_c0, &As[w * 512]);
            load_lds16(A + (size_t)a_r1 * GK + k0 + a_c1, &As[2048 + w * 512]);
            load_lds16(W + (size_t)b_r0 * GK + k0 + a_c0, &Bs[w * 512]);
            load_lds16(W + (size_t)b_r1 * GK + k0 + a_c1, &Bs[2048 + w * 512]);
            __syncthreads();
            short8 af[4], bf[4];
#pragma unroll
            for (int mi = 0; mi < 4; mi++)
                af[mi] = *(const short8*)&As[(wr + mi * 16 + l16) * 32 + quad * 8];
#pragma unroll
            for (int ni = 0; ni < 4; ni++)
                bf[ni] = *(const short8*)&Bs[(wc + ni * 16 + l16) * 32 + quad * 8];
#pragma unroll
            for (int mi = 0; mi < 4; mi++)
#pragma unroll
                for (int ni = 0; ni < 4; ni++)
                    acc[mi][ni] = __builtin_amdgcn_mfma_f32_16x16x32_bf16(
                        bf[ni], af[mi], acc[mi][ni], 0, 0, 0);
        }
        unsigned short* dst = (which == 0) ? qb : kb;
        float sc = (which == 0) ? 0.125f : 1.0f;
#pragma unroll
        for (int mi = 0; mi < 4; mi++) {
            int m = m0 + wr + mi * 16 + l16;
            if (m < M_) {
                int bb = m / N_;
                int i  = m - bb * N_;
                unsigned short* row = dst + ((size_t)(bb * H_ + h) * N_ + i) * HD_;
#pragma unroll
                for (int ni = 0; ni < 4; ni++) {
                    ushort4 pk;
                    pk.x = bf16u(acc[mi][ni][0] * sc);
                    pk.y = bf16u(acc[mi][ni][1] * sc);
                    pk.z = bf16u(acc[mi][ni][2] * sc);
                    pk.w = bf16u(acc[mi][ni][3] * sc);
                    *(ushort4*)(row + ni * 16 + quad * 4) = pk;
                }
            }
        }
    } else {
        for (int k0 = 0; k0 < GK; k0 += 32) {
            __syncthreads();
            load_lds16(A + (size_t)a_r0 * GK + k0 + a_c0, &As[w * 512]);
            load_lds16(A + (size_t)a_r1 * GK + k0 + a_c1, &As[2048 + w * 512]);
            load_lds16(W + (size_t)b_r0 * GK + k0 + a_c0, &Bs[w * 512]);
            load_lds16(W + (size_t)b_r1 * GK + k0 + a_c1, &Bs[2048 + w * 512]);
            __syncthreads();
            short8 af[4], bf[4];
#pragma unroll
            for (int mi = 0; mi < 4; mi++)
                af[mi] = *(const short8*)&As[(wr + mi * 16 + l16) * 32 + quad * 8];
#pragma unroll
            for (int ni = 0; ni < 4; ni++)
                bf[ni] = *(const short8*)&Bs[(wc + ni * 16 + l16) * 32 + quad * 8];
#pragma unroll
            for (int mi = 0; mi < 4; mi++)
#pragma unroll
                for (int ni = 0; ni < 4; ni++)
                    acc[mi][ni] = __builtin_amdgcn_mfma_f32_16x16x32_bf16(
                        af[mi], bf[ni], acc[mi][ni], 0, 0, 0);
        }
#pragma unroll
        for (int mi = 0; mi < 4; mi++)
#pragma unroll
            for (int reg = 0; reg < 4; reg++) {
                int m = m0 + wr + mi * 16 + quad * 4 + reg;
                if (m < M_) {
                    int bb = m / N_;
                    int i  = m - bb * N_;
                    int ch = i >> 5, key = i & 31;
                    size_t base = ((size_t)(bb * H_ + h) * VST + ch) * VCS + key;
#pragma unroll
                    for (int ni = 0; ni < 4; ni++)
                        vtc[base + (size_t)(ni * 16 + l16) * 32] = bf16u(acc[mi][ni][reg]);
                }
            }
    }
}

__global__ __launch_bounds__(256) void gemm_proj_mfma(
        const unsigned short* __restrict__ A, const unsigned short* __restrict__ W,
        const float* __restrict__ bias, float* __restrict__ out) {
    __shared__ __align__(16) unsigned short As[128 * 32];
    __shared__ __align__(16) unsigned short Bs[128 * 32];
    int tid = threadIdx.x;
    int w = tid >> 6, lane = tid & 63;
    int quad = lane >> 4, l16 = lane & 15;
    int m0 = blockIdx.y * 128;
    int n0 = blockIdx.x * 128;
    int wr = (w >> 1) * 64, wc = (w & 1) * 64;

    int c0 = tid, c1 = tid + 256;
    int a_r0 = min(m0 + (c0 >> 2), M_ - 1), a_c0 = (c0 & 3) * 8;
    int a_r1 = min(m0 + (c1 >> 2), M_ - 1), a_c1 = (c1 & 3) * 8;
    int b_r0 = n0 + (c0 >> 2), b_r1 = n0 + (c1 >> 2);

    f32x4 acc[4][4];
    const f32x4 zero4 = {0.f, 0.f, 0.f, 0.f};
#pragma unroll
    for (int mi = 0; mi < 4; mi++)
#pragma unroll
        for (int ni = 0; ni < 4; ni++) acc[mi][ni] = zero4;

    for (int k0 = 0; k0 < GK; k0 += 32) {
        __syncthreads();
        load_lds16(A + (size_t)a_r0 * GK + k0 + a_c0, &As[w * 512]);
        load_lds16(A + (size_t)a_r1 * GK + k0 + a_c1, &As[2048 + w * 512]);
        load_lds16(W + (size_t)b_r0 * GK + k0 + a_c0, &Bs[w * 512]);
        load_lds16(W + (size_t)b_r1 * GK + k0 + a_c1, &Bs[2048 + w * 512]);
        __syncthreads();
        short8 af[4], bf[4];
#pragma unroll
        for (int mi = 0; mi < 4; mi++)
            af[mi] = *(const short8*)&As[(wr + mi * 16 + l16) * 32 + quad * 8];
#pragma unroll
        for (int ni = 0; ni < 4; ni++)
            bf[ni] = *(const short8*)&Bs[(wc + ni * 16 + l16) * 32 + quad * 8];
#pragma unroll
        for (int mi = 0; mi < 4; mi++)
#pragma unroll
            for (int ni = 0; ni < 4; ni++)
                acc[mi][ni] = __builtin_amdgcn_mfma_f32_16x16x32_bf16(
                    af[mi], bf[ni], acc[mi][ni], 0, 0, 0);
    }

    float bvals[4];
#pragma unroll
    for (int ni = 0; ni < 4; ni++) bvals[ni] = bias[n0 + wc + ni * 16 + l16];
#pragma unroll
    for (int mi = 0; mi < 4; mi++)
#pragma unroll
        for (int reg = 0; reg < 4; reg++) {
            int m = m0 + wr + mi * 16 + quad * 4 + reg;
            if (m < M_) {
                float* row = out + (size_t)m * C_ + n0 + wc;
#pragma unroll
                for (int ni = 0; ni < 4; ni++)
                    row[ni * 16 + l16] = acc[mi][ni][reg] + bvals[ni];
            }
        }
}

// ---------------------------------------------------------------------------
// FUSED attention, tail-free grid: 512 blocks (8 xcd x 8 bhi x 8 row-tiles)
// x 576 threads = 9 waves; each wave owns 16 rows, tile covers 144 rows
// (8 x 144 = 1152 >= 1025; pad rows clamp reads, skip stores). All 512
// blocks co-resident (2/CU, 62 KB LDS) -> ONE round, no 64-block tail
// (R13's 576-block grid ran a second half-idle round). Per key-tile:
// K staged to LDS (double-buffered global_load_lds, one barrier), 16 QK
// MFMAs/wave, exp+bias -> per-wave LDS P (no barrier), 20 PV MFMAs/wave
// with V direct from global vtc. P never reaches HBM.
// ---------------------------------------------------------------------------
#define RT_ 144   // rows per tile (9 waves x 16)

__global__ __launch_bounds__(576) void attn_fused(
        const unsigned short* __restrict__ qg,
        const unsigned short* __restrict__ kg,
        const unsigned short* __restrict__ vtc,
        const float* __restrict__ tab,
        unsigned short* __restrict__ ob) {
    // Ks chunk ch = ct*128 + oct*16 + k16 holds K[key=t*128+ct*16+k16][oct*8..+8]
    // padded to 1152 chunks so 576-thread staging's 2nd round overruns into
    // dead tail (ch 1024..1151) instead of the next array.
    __shared__ __align__(16) unsigned short Ks[2][9216];   // 36.9 KB
    __shared__ __align__(16) unsigned short Pw[9][16 * 72];// 20.7 KB, per-wave
    __shared__ float tabs[34 * 33];                        // 4.5 KB

    int tid = threadIdx.x;
    int w = tid >> 6, lane = tid & 63;
    int quad = lane >> 4, l16 = lane & 15;

    int lin = blockIdx.x;
    int xcd = lin & 7;
    int u = lin >> 3;
    int bhi = u & 7;
    int mt = u >> 3;                 // 0..7
    int bh = xcd * 8 + bhi;
    int b = bh >> 3, h = bh & 7;

    const unsigned short* qp = qg + (size_t)bh * N_ * HD_;
    const unsigned short* kp = kg + (size_t)bh * N_ * HD_;
    const unsigned short* vp = vtc + (size_t)bh * VST * VCS;

    for (int i = tid; i < 1024; i += 576)
        tabs[(i >> 5) * 33 + (i & 31)] = tab[h * 1024 + i];

    // Q fragments: wave owns rows mt*144 + w*16 + l16 (A-layout, clamped)
    short8 qf[2];
    {
        int row = min(mt * RT_ + w * 16 + l16, N_ - 1);
        qf[0] = *(const short8*)(qp + (size_t)row * HD_ + quad * 8);
        qf[1] = *(const short8*)(qp + (size_t)row * HD_ + 32 + quad * 8);
    }

    // row-side bias constants (C-layout rows: quad*4+reg)
    int rpx[4], rpy[4];
    bool rz[4];
#pragma unroll
    for (int reg = 0; reg < 4; reg++) {
        int r = mt * RT_ + w * 16 + quad * 4 + reg;
        int ri = min(max(r - 1, 0), N_ - 2);
        rpx[reg] = ri >> 5;
        rpy[reg] = ri & 31;
        rz[reg] = (r == 0);
    }

    f32x4 o_acc[4], l_acc;
    const f32x4 zero4 = {0.f, 0.f, 0.f, 0.f};
#pragma unroll
    for (int g2 = 0; g2 < 4; g2++) o_acc[g2] = zero4;
    l_acc = zero4;
    short8 ones;
    {
        short one_bf = (short)0x3F80;
#pragma unroll
        for (int j = 0; j < 8; j++) ones[j] = one_bf;
    }

    auto stage = [&](int t, int buf) {
#pragma unroll
        for (int r2 = 0; r2 < 2; r2++) {
            int ch = r2 * 576 + tid;         // 0..1151 (>=1024 lands in pad)
            int ct = ch >> 7, rem = ch & 127;
            int oct = rem >> 4, k16 = rem & 15;
            int key = min(t * 128 + ct * 16 + k16, N_ - 1);
            load_lds16(kp + (size_t)key * HD_ + oct * 8,
                       &Ks[buf][(r2 * 576 + w * 64) * 8]);
        }
    };

    stage(0, 0);

#pragma unroll 1
    for (int t = 0; t < 9; t++) {
        int buf = t & 1;
        __syncthreads();                  // Ks[buf] ready (vmcnt drained)
        if (t < 8) stage(t + 1, buf ^ 1);

        // ---- QK: S[16 rows][128 cols] = 8 ct tiles ----
        f32x4 s[8];
#pragma unroll
        for (int ct = 0; ct < 8; ct++) {
            short8 b0 = *(const short8*)&Ks[buf][(ct * 128 + quad * 16 + l16) * 8];
            short8 b1 = *(const short8*)&Ks[buf][(ct * 128 + (4 + quad) * 16 + l16) * 8];
            s[ct] = __builtin_amdgcn_mfma_f32_16x16x32_bf16(qf[0], b0, zero4, 0, 0, 0);
            s[ct] = __builtin_amdgcn_mfma_f32_16x16x32_bf16(qf[1], b1, s[ct], 0, 0, 0);
        }

        // ---- two col-halves: exp+pack (per-wave LDS), then PV ----
#pragma unroll
        for (int hh = 0; hh < 2; hh++) {
#pragma unroll
            for (int ct2 = 0; ct2 < 4; ct2++) {
                int ct = hh * 4 + ct2;
                int col = t * 128 + ct * 16 + l16;
                int ji = col - 1;
                int cx = ji >> 5, cy = ji & 31;
                bool cz = (col == 0), co = (col >= N_);
#pragma unroll
                for (int reg = 0; reg < 4; reg++) {
                    float bia = 0.f;
                    if (!rz[reg] && !cz) {
                        int da = __sad(rpx[reg], cx, 0u);
                        int db = __sad(rpy[reg], cy, 0u);
                        bia = tabs[da * 33 + db];
                    }
                    float p = co ? 0.f : __expf(s[ct][reg] + bia);
                    Pw[w][(quad * 4 + reg) * 72 + ct2 * 16 + l16] = bf16u(p);
                }
            }
            // PV for this 64-key half (2 k-steps of 32)
#pragma unroll
            for (int ks = 0; ks < 2; ks++) {
                int vc = t * 4 + hh * 2 + ks;
                short8 pf = *(const short8*)&Pw[w][l16 * 72 + ks * 32 + quad * 8];
                const unsigned short* vcp = vp + (size_t)vc * VCS + quad * 8;
#pragma unroll
                for (int g2 = 0; g2 < 4; g2++) {
                    short8 vf = *(const short8*)(vcp + (g2 * 16 + l16) * 32);
                    o_acc[g2] = __builtin_amdgcn_mfma_f32_16x16x32_bf16(
                        pf, vf, o_acc[g2], 0, 0, 0);
                }
                l_acc = __builtin_amdgcn_mfma_f32_16x16x32_bf16(pf, ones, l_acc, 0, 0, 0);
            }
        }
    }

    // ---- epilogue: o/l -> ob bf16 (C-layout rows; pad rows skip store) ----
#pragma unroll
    for (int reg = 0; reg < 4; reg++) {
        int r = mt * RT_ + w * 16 + quad * 4 + reg;
        if (r < N_) {
            float inv = 1.0f / l_acc[reg];
            unsigned short* orow = ob + ((size_t)b * N_ + r) * C_ + h * HD_ + l16;
#pragma unroll
            for (int g2 = 0; g2 < 4; g2++)
                orow[g2 * 16] = bf16u(o_acc[g2][reg] * inv);
        }
    }
}

// ---------------------------------------------------------------------------
extern "C" void kernel_launch(void* const* d_in, const int* in_sizes, int n_in,
                              void* d_out, int out_size, void* d_ws, size_t ws_size,
                              hipStream_t stream) {
    const float* x      = (const float*)d_in[0];
    const float* qkv_w  = (const float*)d_in[1];
    const float* proj_w = (const float*)d_in[2];
    const float* proj_b = (const float*)d_in[3];
    const float* wg_w   = (const float*)d_in[4];
    const float* wg_b   = (const float*)d_in[5];
    float* out = (float*)d_out;

    const size_t per = PER_;
    char* ws = (char*)d_ws;
    float* tab            = (float*)ws;                           // 32 KB
    unsigned short* xb    = (unsigned short*)(ws + (32 << 10));   // 8,396,800 B
    unsigned short* wqkvb = xb + per;                             // 1,572,864 B
    unsigned short* wprjb = wqkvb + (size_t)SZ_QKVW;              //   524,288 B
    unsigned short* qb    = wprjb + (size_t)SZ_PRJW;              // 8,396,800 B
    unsigned short* kb    = qb + per;                             // 8,396,800 B
    unsigned short* vtc   = kb + per;                             // 9,437,184 B
    unsigned short* ob    = vtc + (size_t)64 * VST * VCS;         // 8,396,800 B

    prep_kernel<<<32 + CAST_BLKS, 256, 0, stream>>>(x, qkv_w, proj_w, wg_w, wg_b,
                                                    xb, wqkvb, wprjb, tab);
    gemm_qkv_mfma<<<dim3(12, 65), 256, 0, stream>>>(xb, wqkvb, qb, kb, vtc);
    attn_fused<<<8 * 8 * 8, 576, 0, stream>>>(qb, kb, vtc, tab, ob);
    gemm_proj_mfma<<<dim3(4, 65), 256, 0, stream>>>(ob, wprjb, proj_b, out);
}

// Round 15
// 210.402 us; speedup vs baseline: 1.3109x; 1.0846x over previous
//
#include <hip/hip_runtime.h>
#include <hip/hip_bf16.h>
#include <math.h>

#define B_  8
#define N_  1025
#define C_  512
#define H_  8
#define HD_ 64
#define M_  (B_ * N_)   // 8200
#define VCS 2048        // shorts per vtc chunk: 64 dims * 32 keys
#define VST 36          // vtc chunks per bh (33 used + 3 pad for tile 8)

typedef __attribute__((ext_vector_type(8))) short short8;
typedef __attribute__((ext_vector_type(4))) float f32x4;

__device__ inline unsigned short bf16u(float x) {
    __hip_bfloat16 t = __float2bfloat16(x);
    return *(unsigned short*)&t;
}
__device__ inline void load_lds16(const void* g, void* l) {
    __builtin_amdgcn_global_load_lds(
        (const __attribute__((address_space(1))) unsigned int*)g,
        (__attribute__((address_space(3))) unsigned int*)l, 16, 0, 0);
}

// ---------------------------------------------------------------------------
// Fused prep: blocks 0..31 build the H x 32 x 32 bias table; rest cast to bf16.
// ---------------------------------------------------------------------------
#define PER_ ((size_t)B_ * H_ * N_ * HD_)      // 4,198,400
#define SZ_QKVW (3 * C_ * C_)
#define SZ_PRJW (C_ * C_)
#define CAST_BLKS ((4198400 + 786432 + 262144) / 4 / 256)   // 5124

__global__ void prep_kernel(const float* __restrict__ x,
                            const float* __restrict__ qkv_w,
                            const float* __restrict__ proj_w,
                            const float* __restrict__ wg_w,
                            const float* __restrict__ wg_b,
                            unsigned short* __restrict__ xb,
                            unsigned short* __restrict__ wqkvb,
                            unsigned short* __restrict__ wprjb,
                            float* __restrict__ tab) {
    int blk = blockIdx.x;
    int tid = threadIdx.x;
    if (blk < 32) {
        int idx = blk * 256 + tid;
        int h = idx >> 10;
        int a = (idx >> 5) & 31;
        int b = idx & 31;
        float dx = logf(fmaxf((float)a * (1.0f / 33.0f), 0.001f));
        float dy = logf(fmaxf((float)b * (1.0f / 33.0f), 0.001f));
        const float* w = wg_w + h * 64;
        float acc = wg_b[h];
#pragma unroll
        for (int k = 0; k < 8; k++) {
            float f = powf(1000.0f, -(float)k * 0.125f);
            float X = 100.0f * dx * f;
            float Y = 100.0f * dy * f;
            acc += w[k]      * sinf(X);
            acc += w[8 + k]  * sinf(Y);
            acc += w[32 + k] * cosf(X);
            acc += w[40 + k] * cosf(Y);
            acc += w[48 + k] + w[56 + k];
        }
        tab[idx] = logf(fmaxf(fmaxf(acc, 0.0f), 1e-6f));
        return;
    }
    long i4 = ((long)(blk - 32) * 256 + tid) * 4;
    const float* src;
    unsigned short* dst;
    long off;
    if (i4 < (long)PER_)                    { src = x;      dst = xb;    off = i4; }
    else if (i4 < (long)PER_ + SZ_QKVW)     { src = qkv_w;  dst = wqkvb; off = i4 - PER_; }
    else                                    { src = proj_w; dst = wprjb; off = i4 - PER_ - SZ_QKVW; }
    float4 v = *(const float4*)(src + off);
    ushort4 p;
    p.x = bf16u(v.x); p.y = bf16u(v.y); p.z = bf16u(v.z); p.w = bf16u(v.w);
    *(ushort4*)(dst + off) = p;
}

// ---------------------------------------------------------------------------
// MFMA GEMM, 128x128 tile, BK=32, 4 waves. q/k swapped-operand -> ushort4
// stores; v scatters to chunked vtc [bh][ch(VST)][dim][32].
// ---------------------------------------------------------------------------
#define GK 512

__global__ __launch_bounds__(256) void gemm_qkv_mfma(
        const unsigned short* __restrict__ A, const unsigned short* __restrict__ W,
        unsigned short* __restrict__ qb, unsigned short* __restrict__ kb,
        unsigned short* __restrict__ vtc) {
    __shared__ __align__(16) unsigned short As[128 * 32];
    __shared__ __align__(16) unsigned short Bs[128 * 32];
    int tid = threadIdx.x;
    int w = tid >> 6, lane = tid & 63;
    int quad = lane >> 4, l16 = lane & 15;
    int m0 = blockIdx.y * 128;
    int n0 = blockIdx.x * 128;
    int wr = (w >> 1) * 64, wc = (w & 1) * 64;

    int c0 = tid, c1 = tid + 256;
    int a_r0 = min(m0 + (c0 >> 2), M_ - 1), a_c0 = (c0 & 3) * 8;
    int a_r1 = min(m0 + (c1 >> 2), M_ - 1), a_c1 = (c1 & 3) * 8;
    int b_r0 = n0 + (c0 >> 2), b_r1 = n0 + (c1 >> 2);

    int which = n0 >> 9;                       // 0=q 1=k 2=v
    int h = ((n0 + wc) >> 6) & 7;

    f32x4 acc[4][4];
    const f32x4 zero4 = {0.f, 0.f, 0.f, 0.f};
#pragma unroll
    for (int mi = 0; mi < 4; mi++)
#pragma unroll
        for (int ni = 0; ni < 4; ni++) acc[mi][ni] = zero4;

    if (which < 2) {
        for (int k0 = 0; k0 < GK; k0 += 32) {
            __syncthreads();
            load_lds16(A + (size_t)a_r0 * GK + k0 + a_c0, &As[w * 512]);
            load_lds16(A + (size_t)a_r1 * GK + k0 + a_c1, &As[2048 + w * 512]);
            load_lds16(W + (size_t)b_r0 * GK + k0 + a_c0, &Bs[w * 512]);
            load_lds16(W + (size_t)b_r1 * GK + k0 + a_c1, &Bs[2048 + w * 512]);
            __syncthreads();
            short8 af[4], bf[4];
#pragma unroll
            for (int mi = 0; mi < 4; mi++)
                af[mi] = *(const short8*)&As[(wr + mi * 16 + l16) * 32 + quad * 8];
#pragma unroll
            for (int ni = 0; ni < 4; ni++)
                bf[ni] = *(const short8*)&Bs[(wc + ni * 16 + l16) * 32 + quad * 8];
#pragma unroll
            for (int mi = 0; mi < 4; mi++)
#pragma unroll
                for (int ni = 0; ni < 4; ni++)
                    acc[mi][ni] = __builtin_amdgcn_mfma_f32_16x16x32_bf16(
                        bf[ni], af[mi], acc[mi][ni], 0, 0, 0);
        }
        unsigned short* dst = (which == 0) ? qb : kb;
        float sc = (which == 0) ? 0.125f : 1.0f;
#pragma unroll
        for (int mi = 0; mi < 4; mi++) {
            int m = m0 + wr + mi * 16 + l16;
            if (m < M_) {
                int bb = m / N_;
                int i  = m - bb * N_;
                unsigned short* row = dst + ((size_t)(bb * H_ + h) * N_ + i) * HD_;
#pragma unroll
                for (int ni = 0; ni < 4; ni++) {
                    ushort4 pk;
                    pk.x = bf16u(acc[mi][ni][0] * sc);
                    pk.y = bf16u(acc[mi][ni][1] * sc);
                    pk.z = bf16u(acc[mi][ni][2] * sc);
                    pk.w = bf16u(acc[mi][ni][3] * sc);
                    *(ushort4*)(row + ni * 16 + quad * 4) = pk;
                }
            }
        }
    } else {
        for (int k0 = 0; k0 < GK; k0 += 32) {
            __syncthreads();
            load_lds16(A + (size_t)a_r0 * GK + k0 + a_c0, &As[w * 512]);
            load_lds16(A + (size_t)a_r1 * GK + k0 + a_c1, &As[2048 + w * 512]);
            load_lds16(W + (size_t)b_r0 * GK + k0 + a_c0, &Bs[w * 512]);
            load_lds16(W + (size_t)b_r1 * GK + k0 + a_c1, &Bs[2048 + w * 512]);
            __syncthreads();
            short8 af[4], bf[4];
#pragma unroll
            for (int mi = 0; mi < 4; mi++)
                af[mi] = *(const short8*)&As[(wr + mi * 16 + l16) * 32 + quad * 8];
#pragma unroll
            for (int ni = 0; ni < 4; ni++)
                bf[ni] = *(const short8*)&Bs[(wc + ni * 16 + l16) * 32 + quad * 8];
#pragma unroll
            for (int mi = 0; mi < 4; mi++)
#pragma unroll
                for (int ni = 0; ni < 4; ni++)
                    acc[mi][ni] = __builtin_amdgcn_mfma_f32_16x16x32_bf16(
                        af[mi], bf[ni], acc[mi][ni], 0, 0, 0);
        }
#pragma unroll
        for (int mi = 0; mi < 4; mi++)
#pragma unroll
            for (int reg = 0; reg < 4; reg++) {
                int m = m0 + wr + mi * 16 + quad * 4 + reg;
                if (m < M_) {
                    int bb = m / N_;
                    int i  = m - bb * N_;
                    int ch = i >> 5, key = i & 31;
                    size_t base = ((size_t)(bb * H_ + h) * VST + ch) * VCS + key;
#pragma unroll
                    for (int ni = 0; ni < 4; ni++)
                        vtc[base + (size_t)(ni * 16 + l16) * 32] = bf16u(acc[mi][ni][reg]);
                }
            }
    }
}

__global__ __launch_bounds__(256) void gemm_proj_mfma(
        const unsigned short* __restrict__ A, const unsigned short* __restrict__ W,
        const float* __restrict__ bias, float* __restrict__ out) {
    __shared__ __align__(16) unsigned short As[128 * 32];
    __shared__ __align__(16) unsigned short Bs[128 * 32];
    int tid = threadIdx.x;
    int w = tid >> 6, lane = tid & 63;
    int quad = lane >> 4, l16 = lane & 15;
    int m0 = blockIdx.y * 128;
    int n0 = blockIdx.x * 128;
    int wr = (w >> 1) * 64, wc = (w & 1) * 64;

    int c0 = tid, c1 = tid + 256;
    int a_r0 = min(m0 + (c0 >> 2), M_ - 1), a_c0 = (c0 & 3) * 8;
    int a_r1 = min(m0 + (c1 >> 2), M_ - 1), a_c1 = (c1 & 3) * 8;
    int b_r0 = n0 + (c0 >> 2), b_r1 = n0 + (c1 >> 2);

    f32x4 acc[4][4];
    const f32x4 zero4 = {0.f, 0.f, 0.f, 0.f};
#pragma unroll
    for (int mi = 0; mi < 4; mi++)
#pragma unroll
        for (int ni = 0; ni < 4; ni++) acc[mi][ni] = zero4;

    for (int k0 = 0; k0 < GK; k0 += 32) {
        __syncthreads();
        load_lds16(A + (size_t)a_r0 * GK + k0 + a_c0, &As[w * 512]);
        load_lds16(A + (size_t)a_r1 * GK + k0 + a_c1, &As[2048 + w * 512]);
        load_lds16(W + (size_t)b_r0 * GK + k0 + a_c0, &Bs[w * 512]);
        load_lds16(W + (size_t)b_r1 * GK + k0 + a_c1, &Bs[2048 + w * 512]);
        __syncthreads();
        short8 af[4], bf[4];
#pragma unroll
        for (int mi = 0; mi < 4; mi++)
            af[mi] = *(const short8*)&As[(wr + mi * 16 + l16) * 32 + quad * 8];
#pragma unroll
        for (int ni = 0; ni < 4; ni++)
            bf[ni] = *(const short8*)&Bs[(wc + ni * 16 + l16) * 32 + quad * 8];
#pragma unroll
        for (int mi = 0; mi < 4; mi++)
#pragma unroll
            for (int ni = 0; ni < 4; ni++)
                acc[mi][ni] = __builtin_amdgcn_mfma_f32_16x16x32_bf16(
                    af[mi], bf[ni], acc[mi][ni], 0, 0, 0);
    }

    float bvals[4];
#pragma unroll
    for (int ni = 0; ni < 4; ni++) bvals[ni] = bias[n0 + wc + ni * 16 + l16];
#pragma unroll
    for (int mi = 0; mi < 4; mi++)
#pragma unroll
        for (int reg = 0; reg < 4; reg++) {
            int m = m0 + wr + mi * 16 + quad * 4 + reg;
            if (m < M_) {
                float* row = out + (size_t)m * C_ + n0 + wc;
#pragma unroll
                for (int ni = 0; ni < 4; ni++)
                    row[ni * 16 + l16] = acc[mi][ni][reg] + bvals[ni];
            }
        }
}

// ---------------------------------------------------------------------------
// FUSED attention v3: V STAGED IN LDS (R14's V came from global per wave ->
// 9x redundant L2 reads per block, the measured bottleneck). 512 blocks
// (8 xcd x 8 bhi x 8 row-tiles) x 576 thr = 9 waves x 16 rows (144 rows/tile,
// pad rows clamp reads / skip stores). Per key-tile of 128: K AND V staged
// via double-buffered global_load_lds (waves 0-7 stage 1024 chunks each;
// wave 9 computes only), ONE barrier/iter; 16 QK MFMAs/wave; then 4 steps
// of 32 cols: exp+bias -> per-wave LDS P (stride 40, 16B-aligned), 5 PV
// MFMAs from LDS V. LDS = 32K(Ks)+32K(Vs)+11.5K(Pw)+4.4K(tabs) = 81,412 B
// -> rounds to exactly 80 KB -> 2 blocks/CU, 18 waves/CU.
// ---------------------------------------------------------------------------
#define RT_ 144   // rows per tile (9 waves x 16)

__global__ __launch_bounds__(576) void attn_fused(
        const unsigned short* __restrict__ qg,
        const unsigned short* __restrict__ kg,
        const unsigned short* __restrict__ vtc,
        const float* __restrict__ tab,
        unsigned short* __restrict__ ob) {
    // Ks chunk ch = ct*128 + oct*16 + k16 holds K[key=t*128+ct*16+k16][oct*8..+8]
    __shared__ __align__(16) unsigned short Ks[2][8192];   // 32 KB
    __shared__ __align__(16) unsigned short Vs[2][8192];   // 32 KB ([ch][dim][32] x4)
    __shared__ __align__(16) unsigned short Pw[9][16 * 40];// 11.5 KB, per-wave
    __shared__ float tabs[1089];                           // 4.4 KB (33x33)

    int tid = threadIdx.x;
    int w = tid >> 6, lane = tid & 63;
    int quad = lane >> 4, l16 = lane & 15;

    int lin = blockIdx.x;
    int xcd = lin & 7;
    int u = lin >> 3;
    int bhi = u & 7;
    int mt = u >> 3;                 // 0..7
    int bh = xcd * 8 + bhi;
    int b = bh >> 3, h = bh & 7;

    const unsigned short* qp = qg + (size_t)bh * N_ * HD_;
    const unsigned short* kp = kg + (size_t)bh * N_ * HD_;
    const unsigned short* vp = vtc + (size_t)bh * VST * VCS;

    for (int i = tid; i < 1024; i += 576)
        tabs[(i >> 5) * 33 + (i & 31)] = tab[h * 1024 + i];

    // Q fragments: wave owns rows mt*144 + w*16 + l16 (A-layout, clamped)
    short8 qf[2];
    {
        int row = min(mt * RT_ + w * 16 + l16, N_ - 1);
        qf[0] = *(const short8*)(qp + (size_t)row * HD_ + quad * 8);
        qf[1] = *(const short8*)(qp + (size_t)row * HD_ + 32 + quad * 8);
    }

    // row-side bias constants (C-layout rows: quad*4+reg)
    int rpx[4], rpy[4];
    bool rz[4];
#pragma unroll
    for (int reg = 0; reg < 4; reg++) {
        int r = mt * RT_ + w * 16 + quad * 4 + reg;
        int ri = min(max(r - 1, 0), N_ - 2);
        rpx[reg] = ri >> 5;
        rpy[reg] = ri & 31;
        rz[reg] = (r == 0);
    }

    f32x4 o_acc[4], l_acc;
    const f32x4 zero4 = {0.f, 0.f, 0.f, 0.f};
#pragma unroll
    for (int g2 = 0; g2 < 4; g2++) o_acc[g2] = zero4;
    l_acc = zero4;
    short8 ones;
    {
        short one_bf = (short)0x3F80;
#pragma unroll
        for (int j = 0; j < 8; j++) ones[j] = one_bf;
    }

    // staging: waves 0-7 (512 threads) stage 1024 16B-chunks of K and of V
    auto stage = [&](int t, int buf) {
        if (w < 8) {
#pragma unroll
            for (int r2 = 0; r2 < 2; r2++) {
                int ch = r2 * 512 + tid;         // 0..1023
                int ct = ch >> 7, rem = ch & 127;
                int oct = rem >> 4, k16 = rem & 15;
                int key = min(t * 128 + ct * 16 + k16, N_ - 1);
                load_lds16(kp + (size_t)key * HD_ + oct * 8,
                           &Ks[buf][(r2 * 512 + w * 64) * 8]);
                // V: verbatim copy of vtc chunks 4t..4t+3 (chunk-linear)
                load_lds16(vp + ((size_t)t * 4 * VCS) + (size_t)ch * 8,
                           &Vs[buf][(r2 * 512 + w * 64) * 8]);
            }
        }
    };

    stage(0, 0);

#pragma unroll 1
    for (int t = 0; t < 9; t++) {
        int buf = t & 1;
        __syncthreads();                  // Ks/Vs[buf] ready (vmcnt drained)
        if (t < 8) stage(t + 1, buf ^ 1);

        // ---- QK: S[16 rows][128 cols] = 8 ct tiles ----
        f32x4 s[8];
#pragma unroll
        for (int ct = 0; ct < 8; ct++) {
            short8 b0 = *(const short8*)&Ks[buf][(ct * 128 + quad * 16 + l16) * 8];
            short8 b1 = *(const short8*)&Ks[buf][(ct * 128 + (4 + quad) * 16 + l16) * 8];
            s[ct] = __builtin_amdgcn_mfma_f32_16x16x32_bf16(qf[0], b0, zero4, 0, 0, 0);
            s[ct] = __builtin_amdgcn_mfma_f32_16x16x32_bf16(qf[1], b1, s[ct], 0, 0, 0);
        }

        // ---- 4 steps of 32 cols: exp+pack (per-wave LDS), then PV ----
#pragma unroll
        for (int ks = 0; ks < 4; ks++) {
#pragma unroll
            for (int ctl = 0; ctl < 2; ctl++) {
                int ct = ks * 2 + ctl;
                int col = t * 128 + ct * 16 + l16;
                int ji = col - 1;
                int cx = ji >> 5, cy = ji & 31;
                bool cz = (col == 0), co = (col >= N_);
#pragma unroll
                for (int reg = 0; reg < 4; reg++) {
                    float bia = 0.f;
                    if (!rz[reg] && !cz) {
                        int da = __sad(rpx[reg], cx, 0u);
                        int db = __sad(rpy[reg], cy, 0u);
                        bia = tabs[da * 33 + db];
                    }
                    float p = co ? 0.f : __expf(s[ct][reg] + bia);
                    Pw[w][(quad * 4 + reg) * 40 + ctl * 16 + l16] = bf16u(p);
                }
            }
            // PV for this 32-key step; V from LDS (chunk vc local = ks)
            short8 pf = *(const short8*)&Pw[w][l16 * 40 + quad * 8];
            const unsigned short* vcp = &Vs[buf][ks * 2048 + quad * 8];
#pragma unroll
            for (int g2 = 0; g2 < 4; g2++) {
                short8 vf = *(const short8*)(vcp + (g2 * 16 + l16) * 32);
                o_acc[g2] = __builtin_amdgcn_mfma_f32_16x16x32_bf16(
                    pf, vf, o_acc[g2], 0, 0, 0);
            }
            l_acc = __builtin_amdgcn_mfma_f32_16x16x32_bf16(pf, ones, l_acc, 0, 0, 0);
        }
    }

    // ---- epilogue: o/l -> ob bf16 (C-layout rows; pad rows skip store) ----
#pragma unroll
    for (int reg = 0; reg < 4; reg++) {
        int r = mt * RT_ + w * 16 + quad * 4 + reg;
        if (r < N_) {
            float inv = 1.0f / l_acc[reg];
            unsigned short* orow = ob + ((size_t)b * N_ + r) * C_ + h * HD_ + l16;
#pragma unroll
            for (int g2 = 0; g2 < 4; g2++)
                orow[g2 * 16] = bf16u(o_acc[g2][reg] * inv);
        }
    }
}

// ---------------------------------------------------------------------------
extern "C" void kernel_launch(void* const* d_in, const int* in_sizes, int n_in,
                              void* d_out, int out_size, void* d_ws, size_t ws_size,
                              hipStream_t stream) {
    const float* x      = (const float*)d_in[0];
    const float* qkv_w  = (const float*)d_in[1];
    const float* proj_w = (const float*)d_in[2];
    const float* proj_b = (const float*)d_in[3];
    const float* wg_w   = (const float*)d_in[4];
    const float* wg_b   = (const float*)d_in[5];
    float* out = (float*)d_out;

    const size_t per = PER_;
    char* ws = (char*)d_ws;
    float* tab            = (float*)ws;                           // 32 KB
    unsigned short* xb    = (unsigned short*)(ws + (32 << 10));   // 8,396,800 B
    unsigned short* wqkvb = xb + per;                             // 1,572,864 B
    unsigned short* wprjb = wqkvb + (size_t)SZ_QKVW;              //   524,288 B
    unsigned short* qb    = wprjb + (size_t)SZ_PRJW;              // 8,396,800 B
    unsigned short* kb    = qb + per;                             // 8,396,800 B
    unsigned short* vtc   = kb + per;                             // 9,437,184 B
    unsigned short* ob    = vtc + (size_t)64 * VST * VCS;         // 8,396,800 B

    prep_kernel<<<32 + CAST_BLKS, 256, 0, stream>>>(x, qkv_w, proj_w, wg_w, wg_b,
                                                    xb, wqkvb, wprjb, tab);
    gemm_qkv_mfma<<<dim3(12, 65), 256, 0, stream>>>(xb, wqkvb, qb, kb, vtc);
    attn_fused<<<8 * 8 * 8, 576, 0, stream>>>(qb, kb, vtc, tab, ob);
    gemm_proj_mfma<<<dim3(4, 65), 256, 0, stream>>>(ob, wprjb, proj_b, out);
}

// Round 16
// 203.389 us; speedup vs baseline: 1.3561x; 1.0345x over previous
//
#include <hip/hip_runtime.h>
#include <hip/hip_bf16.h>
#include <math.h>

#define B_  8
#define N_  1025
#define C_  512
#define H_  8
#define HD_ 64
#define M_  (B_ * N_)   // 8200
#define VCS 2048        // shorts per vtc chunk: 64 dims * 32 keys
#define VST 36          // vtc chunks per bh (33 used + 3 pad for tile 8)

typedef __attribute__((ext_vector_type(8))) short short8;
typedef __attribute__((ext_vector_type(4))) float f32x4;

__device__ inline unsigned short bf16u(float x) {
    __hip_bfloat16 t = __float2bfloat16(x);
    return *(unsigned short*)&t;
}
__device__ inline void load_lds16(const void* g, void* l) {
    __builtin_amdgcn_global_load_lds(
        (const __attribute__((address_space(1))) unsigned int*)g,
        (__attribute__((address_space(3))) unsigned int*)l, 16, 0, 0);
}

// ---------------------------------------------------------------------------
// Fused prep: blocks 0..31 build the H x 32 x 32 bias table; rest cast to bf16.
// ---------------------------------------------------------------------------
#define PER_ ((size_t)B_ * H_ * N_ * HD_)      // 4,198,400
#define SZ_QKVW (3 * C_ * C_)
#define SZ_PRJW (C_ * C_)
#define CAST_BLKS ((4198400 + 786432 + 262144) / 4 / 256)   // 5124

__global__ void prep_kernel(const float* __restrict__ x,
                            const float* __restrict__ qkv_w,
                            const float* __restrict__ proj_w,
                            const float* __restrict__ wg_w,
                            const float* __restrict__ wg_b,
                            unsigned short* __restrict__ xb,
                            unsigned short* __restrict__ wqkvb,
                            unsigned short* __restrict__ wprjb,
                            float* __restrict__ tab) {
    int blk = blockIdx.x;
    int tid = threadIdx.x;
    if (blk < 32) {
        int idx = blk * 256 + tid;
        int h = idx >> 10;
        int a = (idx >> 5) & 31;
        int b = idx & 31;
        float dx = logf(fmaxf((float)a * (1.0f / 33.0f), 0.001f));
        float dy = logf(fmaxf((float)b * (1.0f / 33.0f), 0.001f));
        const float* w = wg_w + h * 64;
        float acc = wg_b[h];
#pragma unroll
        for (int k = 0; k < 8; k++) {
            float f = powf(1000.0f, -(float)k * 0.125f);
            float X = 100.0f * dx * f;
            float Y = 100.0f * dy * f;
            acc += w[k]      * sinf(X);
            acc += w[8 + k]  * sinf(Y);
            acc += w[32 + k] * cosf(X);
            acc += w[40 + k] * cosf(Y);
            acc += w[48 + k] + w[56 + k];
        }
        tab[idx] = logf(fmaxf(fmaxf(acc, 0.0f), 1e-6f));
        return;
    }
    long i4 = ((long)(blk - 32) * 256 + tid) * 4;
    const float* src;
    unsigned short* dst;
    long off;
    if (i4 < (long)PER_)                    { src = x;      dst = xb;    off = i4; }
    else if (i4 < (long)PER_ + SZ_QKVW)     { src = qkv_w;  dst = wqkvb; off = i4 - PER_; }
    else                                    { src = proj_w; dst = wprjb; off = i4 - PER_ - SZ_QKVW; }
    float4 v = *(const float4*)(src + off);
    ushort4 p;
    p.x = bf16u(v.x); p.y = bf16u(v.y); p.z = bf16u(v.z); p.w = bf16u(v.w);
    *(ushort4*)(dst + off) = p;
}

// ---------------------------------------------------------------------------
// MFMA GEMM, 128x128 tile, BK=32, 4 waves, UNIFIED swapped-operand MFMA
// (lane = token, reg = feature). q/k: ushort4 row stores. v: key-contiguous
// 2B stores in 16-lane runs (32B segments) to vtc [bh][ch(VST)][dim][32].
// ---------------------------------------------------------------------------
#define GK 512

__global__ __launch_bounds__(256) void gemm_qkv_mfma(
        const unsigned short* __restrict__ A, const unsigned short* __restrict__ W,
        unsigned short* __restrict__ qb, unsigned short* __restrict__ kb,
        unsigned short* __restrict__ vtc) {
    __shared__ __align__(16) unsigned short As[128 * 32];
    __shared__ __align__(16) unsigned short Bs[128 * 32];
    int tid = threadIdx.x;
    int w = tid >> 6, lane = tid & 63;
    int quad = lane >> 4, l16 = lane & 15;
    int m0 = blockIdx.y * 128;
    int n0 = blockIdx.x * 128;
    int wr = (w >> 1) * 64, wc = (w & 1) * 64;

    int c0 = tid, c1 = tid + 256;
    int a_r0 = min(m0 + (c0 >> 2), M_ - 1), a_c0 = (c0 & 3) * 8;
    int a_r1 = min(m0 + (c1 >> 2), M_ - 1), a_c1 = (c1 & 3) * 8;
    int b_r0 = n0 + (c0 >> 2), b_r1 = n0 + (c1 >> 2);

    int which = n0 >> 9;                       // 0=q 1=k 2=v
    int h = ((n0 + wc) >> 6) & 7;

    f32x4 acc[4][4];
    const f32x4 zero4 = {0.f, 0.f, 0.f, 0.f};
#pragma unroll
    for (int mi = 0; mi < 4; mi++)
#pragma unroll
        for (int ni = 0; ni < 4; ni++) acc[mi][ni] = zero4;

    for (int k0 = 0; k0 < GK; k0 += 32) {
        __syncthreads();
        load_lds16(A + (size_t)a_r0 * GK + k0 + a_c0, &As[w * 512]);
        load_lds16(A + (size_t)a_r1 * GK + k0 + a_c1, &As[2048 + w * 512]);
        load_lds16(W + (size_t)b_r0 * GK + k0 + a_c0, &Bs[w * 512]);
        load_lds16(W + (size_t)b_r1 * GK + k0 + a_c1, &Bs[2048 + w * 512]);
        __syncthreads();
        short8 af[4], bf[4];
#pragma unroll
        for (int mi = 0; mi < 4; mi++)
            af[mi] = *(const short8*)&As[(wr + mi * 16 + l16) * 32 + quad * 8];
#pragma unroll
        for (int ni = 0; ni < 4; ni++)
            bf[ni] = *(const short8*)&Bs[(wc + ni * 16 + l16) * 32 + quad * 8];
#pragma unroll
        for (int mi = 0; mi < 4; mi++)
#pragma unroll
            for (int ni = 0; ni < 4; ni++)
                acc[mi][ni] = __builtin_amdgcn_mfma_f32_16x16x32_bf16(
                    bf[ni], af[mi], acc[mi][ni], 0, 0, 0);
    }

    if (which < 2) {
        unsigned short* dst = (which == 0) ? qb : kb;
        float sc = (which == 0) ? 0.125f : 1.0f;
#pragma unroll
        for (int mi = 0; mi < 4; mi++) {
            int m = m0 + wr + mi * 16 + l16;
            if (m < M_) {
                int bb = m / N_;
                int i  = m - bb * N_;
                unsigned short* row = dst + ((size_t)(bb * H_ + h) * N_ + i) * HD_;
#pragma unroll
                for (int ni = 0; ni < 4; ni++) {
                    ushort4 pk;
                    pk.x = bf16u(acc[mi][ni][0] * sc);
                    pk.y = bf16u(acc[mi][ni][1] * sc);
                    pk.z = bf16u(acc[mi][ni][2] * sc);
                    pk.w = bf16u(acc[mi][ni][3] * sc);
                    *(ushort4*)(row + ni * 16 + quad * 4) = pk;
                }
            }
        }
    } else {
        // v: lane = token -> 16 consecutive keys per store inst (coalesced)
#pragma unroll
        for (int mi = 0; mi < 4; mi++) {
            int m = m0 + wr + mi * 16 + l16;
            if (m < M_) {
                int bb = m / N_;
                int i  = m - bb * N_;
                int ch = i >> 5, key = i & 31;
                unsigned short* base = vtc + ((size_t)(bb * H_ + h) * VST + ch) * VCS + key;
#pragma unroll
                for (int ni = 0; ni < 4; ni++)
#pragma unroll
                    for (int reg = 0; reg < 4; reg++)
                        base[(ni * 16 + quad * 4 + reg) * 32] = bf16u(acc[mi][ni][reg]);
            }
        }
    }
}

__global__ __launch_bounds__(256) void gemm_proj_mfma(
        const unsigned short* __restrict__ A, const unsigned short* __restrict__ W,
        const float* __restrict__ bias, float* __restrict__ out) {
    __shared__ __align__(16) unsigned short As[128 * 32];
    __shared__ __align__(16) unsigned short Bs[128 * 32];
    int tid = threadIdx.x;
    int w = tid >> 6, lane = tid & 63;
    int quad = lane >> 4, l16 = lane & 15;
    int m0 = blockIdx.y * 128;
    int n0 = blockIdx.x * 128;
    int wr = (w >> 1) * 64, wc = (w & 1) * 64;

    int c0 = tid, c1 = tid + 256;
    int a_r0 = min(m0 + (c0 >> 2), M_ - 1), a_c0 = (c0 & 3) * 8;
    int a_r1 = min(m0 + (c1 >> 2), M_ - 1), a_c1 = (c1 & 3) * 8;
    int b_r0 = n0 + (c0 >> 2), b_r1 = n0 + (c1 >> 2);

    f32x4 acc[4][4];
    const f32x4 zero4 = {0.f, 0.f, 0.f, 0.f};
#pragma unroll
    for (int mi = 0; mi < 4; mi++)
#pragma unroll
        for (int ni = 0; ni < 4; ni++) acc[mi][ni] = zero4;

    for (int k0 = 0; k0 < GK; k0 += 32) {
        __syncthreads();
        load_lds16(A + (size_t)a_r0 * GK + k0 + a_c0, &As[w * 512]);
        load_lds16(A + (size_t)a_r1 * GK + k0 + a_c1, &As[2048 + w * 512]);
        load_lds16(W + (size_t)b_r0 * GK + k0 + a_c0, &Bs[w * 512]);
        load_lds16(W + (size_t)b_r1 * GK + k0 + a_c1, &Bs[2048 + w * 512]);
        __syncthreads();
        short8 af[4], bf[4];
#pragma unroll
        for (int mi = 0; mi < 4; mi++)
            af[mi] = *(const short8*)&As[(wr + mi * 16 + l16) * 32 + quad * 8];
#pragma unroll
        for (int ni = 0; ni < 4; ni++)
            bf[ni] = *(const short8*)&Bs[(wc + ni * 16 + l16) * 32 + quad * 8];
#pragma unroll
        for (int mi = 0; mi < 4; mi++)
#pragma unroll
            for (int ni = 0; ni < 4; ni++)
                acc[mi][ni] = __builtin_amdgcn_mfma_f32_16x16x32_bf16(
                    af[mi], bf[ni], acc[mi][ni], 0, 0, 0);
    }

    float bvals[4];
#pragma unroll
    for (int ni = 0; ni < 4; ni++) bvals[ni] = bias[n0 + wc + ni * 16 + l16];
#pragma unroll
    for (int mi = 0; mi < 4; mi++)
#pragma unroll
        for (int reg = 0; reg < 4; reg++) {
            int m = m0 + wr + mi * 16 + quad * 4 + reg;
            if (m < M_) {
                float* row = out + (size_t)m * C_ + n0 + wc;
#pragma unroll
                for (int ni = 0; ni < 4; ni++)
                    row[ni * 16 + l16] = acc[mi][ni][reg] + bvals[ni];
            }
        }
}

// ---------------------------------------------------------------------------
// FUSED attention v4: V LDS layout XOR-SWIZZLED. R15's PV V-reads were 8-way
// bank-conflicted per quarter-wave phase (stride-64B within a phase). Chunk c
// now lives at LDS chunk c ^ ((c>>3)&7) (self-inverse, bijective within each
// 256-chunk ks-block); staging permutes the SOURCE chunk (global_load_lds
// dests are lane-linear). Per-phase bank-group becomes
// ((l16&1)*4+quad)^(l16>>1) -> 2 lanes/group = conflict-free.
// Everything else as R15: 512 blocks x 576 thr (9 waves x 16 rows, 144/tile),
// K+V double-buffered via global_load_lds, one barrier/tile, per-wave P LDS,
// l via ones-column MFMA. LDS 80 KB -> 2 blocks/CU.
// ---------------------------------------------------------------------------
#define RT_ 144   // rows per tile (9 waves x 16)

__global__ __launch_bounds__(576) void attn_fused(
        const unsigned short* __restrict__ qg,
        const unsigned short* __restrict__ kg,
        const unsigned short* __restrict__ vtc,
        const float* __restrict__ tab,
        unsigned short* __restrict__ ob) {
    __shared__ __align__(16) unsigned short Ks[2][8192];   // 32 KB
    __shared__ __align__(16) unsigned short Vs[2][8192];   // 32 KB (swizzled)
    __shared__ __align__(16) unsigned short Pw[9][16 * 40];// 11.5 KB, per-wave
    __shared__ float tabs[1089];                           // 4.4 KB (33x33)

    int tid = threadIdx.x;
    int w = tid >> 6, lane = tid & 63;
    int quad = lane >> 4, l16 = lane & 15;

    int lin = blockIdx.x;
    int xcd = lin & 7;
    int u = lin >> 3;
    int bhi = u & 7;
    int mt = u >> 3;                 // 0..7
    int bh = xcd * 8 + bhi;
    int b = bh >> 3, h = bh & 7;

    const unsigned short* qp = qg + (size_t)bh * N_ * HD_;
    const unsigned short* kp = kg + (size_t)bh * N_ * HD_;
    const unsigned short* vp = vtc + (size_t)bh * VST * VCS;

    for (int i = tid; i < 1024; i += 576)
        tabs[(i >> 5) * 33 + (i & 31)] = tab[h * 1024 + i];

    // Q fragments: wave owns rows mt*144 + w*16 + l16 (A-layout, clamped)
    short8 qf[2];
    {
        int row = min(mt * RT_ + w * 16 + l16, N_ - 1);
        qf[0] = *(const short8*)(qp + (size_t)row * HD_ + quad * 8);
        qf[1] = *(const short8*)(qp + (size_t)row * HD_ + 32 + quad * 8);
    }

    // row-side bias constants (C-layout rows: quad*4+reg)
    int rpx[4], rpy[4];
    bool rz[4];
#pragma unroll
    for (int reg = 0; reg < 4; reg++) {
        int r = mt * RT_ + w * 16 + quad * 4 + reg;
        int ri = min(max(r - 1, 0), N_ - 2);
        rpx[reg] = ri >> 5;
        rpy[reg] = ri & 31;
        rz[reg] = (r == 0);
    }

    f32x4 o_acc[4], l_acc;
    const f32x4 zero4 = {0.f, 0.f, 0.f, 0.f};
#pragma unroll
    for (int g2 = 0; g2 < 4; g2++) o_acc[g2] = zero4;
    l_acc = zero4;
    short8 ones;
    {
        short one_bf = (short)0x3F80;
#pragma unroll
        for (int j = 0; j < 8; j++) ones[j] = one_bf;
    }

    // staging: waves 0-7 (512 threads) stage 1024 16B-chunks of K and V.
    // V source chunk is XOR-swizzled so LDS chunk s holds global s^((s>>3)&7).
    auto stage = [&](int t, int buf) {
        if (w < 8) {
#pragma unroll
            for (int r2 = 0; r2 < 2; r2++) {
                int s = r2 * 512 + tid;          // 0..1023 LDS chunk (lane-linear)
                int ct = s >> 7, rem = s & 127;
                int oct = rem >> 4, k16 = rem & 15;
                int key = min(t * 128 + ct * 16 + k16, N_ - 1);
                load_lds16(kp + (size_t)key * HD_ + oct * 8,
                           &Ks[buf][(r2 * 512 + w * 64) * 8]);
                int g = s ^ ((s >> 3) & 7);      // swizzled source chunk
                load_lds16(vp + ((size_t)t * 4 * VCS) + (size_t)g * 8,
                           &Vs[buf][(r2 * 512 + w * 64) * 8]);
            }
        }
    };

    stage(0, 0);

#pragma unroll 1
    for (int t = 0; t < 9; t++) {
        int buf = t & 1;
        __syncthreads();                  // Ks/Vs[buf] ready (vmcnt drained)
        if (t < 8) stage(t + 1, buf ^ 1);

        // ---- QK: S[16 rows][128 cols] = 8 ct tiles ----
        f32x4 s[8];
#pragma unroll
        for (int ct = 0; ct < 8; ct++) {
            short8 b0 = *(const short8*)&Ks[buf][(ct * 128 + quad * 16 + l16) * 8];
            short8 b1 = *(const short8*)&Ks[buf][(ct * 128 + (4 + quad) * 16 + l16) * 8];
            s[ct] = __builtin_amdgcn_mfma_f32_16x16x32_bf16(qf[0], b0, zero4, 0, 0, 0);
            s[ct] = __builtin_amdgcn_mfma_f32_16x16x32_bf16(qf[1], b1, s[ct], 0, 0, 0);
        }

        // ---- 4 steps of 32 cols: exp+pack (per-wave LDS), then PV ----
#pragma unroll
        for (int ks = 0; ks < 4; ks++) {
#pragma unroll
            for (int ctl = 0; ctl < 2; ctl++) {
                int ct = ks * 2 + ctl;
                int col = t * 128 + ct * 16 + l16;
                int ji = col - 1;
                int cx = ji >> 5, cy = ji & 31;
                bool cz = (col == 0), co = (col >= N_);
#pragma unroll
                for (int reg = 0; reg < 4; reg++) {
                    float bia = 0.f;
                    if (!rz[reg] && !cz) {
                        int da = __sad(rpx[reg], cx, 0u);
                        int db = __sad(rpy[reg], cy, 0u);
                        bia = tabs[da * 33 + db];
                    }
                    float p = co ? 0.f : __expf(s[ct][reg] + bia);
                    Pw[w][(quad * 4 + reg) * 40 + ctl * 16 + l16] = bf16u(p);
                }
            }
            // PV for this 32-key step; V from swizzled LDS
            short8 pf = *(const short8*)&Pw[w][l16 * 40 + quad * 8];
#pragma unroll
            for (int g2 = 0; g2 < 4; g2++) {
                int c = (g2 * 16 + l16) * 4 + quad;           // chunk in ks-block
                int cs = c ^ ((c >> 3) & 7);                  // swizzled
                short8 vf = *(const short8*)&Vs[buf][(ks * 256 + cs) * 8];
                o_acc[g2] = __builtin_amdgcn_mfma_f32_16x16x32_bf16(
                    pf, vf, o_acc[g2], 0, 0, 0);
            }
            l_acc = __builtin_amdgcn_mfma_f32_16x16x32_bf16(pf, ones, l_acc, 0, 0, 0);
        }
    }

    // ---- epilogue: o/l -> ob bf16 (C-layout rows; pad rows skip store) ----
#pragma unroll
    for (int reg = 0; reg < 4; reg++) {
        int r = mt * RT_ + w * 16 + quad * 4 + reg;
        if (r < N_) {
            float inv = 1.0f / l_acc[reg];
            unsigned short* orow = ob + ((size_t)b * N_ + r) * C_ + h * HD_ + l16;
#pragma unroll
            for (int g2 = 0; g2 < 4; g2++)
                orow[g2 * 16] = bf16u(o_acc[g2][reg] * inv);
        }
    }
}

// ---------------------------------------------------------------------------
extern "C" void kernel_launch(void* const* d_in, const int* in_sizes, int n_in,
                              void* d_out, int out_size, void* d_ws, size_t ws_size,
                              hipStream_t stream) {
    const float* x      = (const float*)d_in[0];
    const float* qkv_w  = (const float*)d_in[1];
    const float* proj_w = (const float*)d_in[2];
    const float* proj_b = (const float*)d_in[3];
    const float* wg_w   = (const float*)d_in[4];
    const float* wg_b   = (const float*)d_in[5];
    float* out = (float*)d_out;

    const size_t per = PER_;
    char* ws = (char*)d_ws;
    float* tab            = (float*)ws;                           // 32 KB
    unsigned short* xb    = (unsigned short*)(ws + (32 << 10));   // 8,396,800 B
    unsigned short* wqkvb = xb + per;                             // 1,572,864 B
    unsigned short* wprjb = wqkvb + (size_t)SZ_QKVW;              //   524,288 B
    unsigned short* qb    = wprjb + (size_t)SZ_PRJW;              // 8,396,800 B
    unsigned short* kb    = qb + per;                             // 8,396,800 B
    unsigned short* vtc   = kb + per;                             // 9,437,184 B
    unsigned short* ob    = vtc + (size_t)64 * VST * VCS;         // 8,396,800 B

    prep_kernel<<<32 + CAST_BLKS, 256, 0, stream>>>(x, qkv_w, proj_w, wg_w, wg_b,
                                                    xb, wqkvb, wprjb, tab);
    gemm_qkv_mfma<<<dim3(12, 65), 256, 0, stream>>>(xb, wqkvb, qb, kb, vtc);
    attn_fused<<<8 * 8 * 8, 576, 0, stream>>>(qb, kb, vtc, tab, ob);
    gemm_proj_mfma<<<dim3(4, 65), 256, 0, stream>>>(ob, wprjb, proj_b, out);
}

// Round 17
// 198.360 us; speedup vs baseline: 1.3905x; 1.0254x over previous
//
#include <hip/hip_runtime.h>
#include <hip/hip_bf16.h>
#include <math.h>

#define B_  8
#define N_  1025
#define C_  512
#define H_  8
#define HD_ 64
#define M_  (B_ * N_)   // 8200
#define VCS 2048        // shorts per vtc chunk-block: 64 dims * 32 keys
#define VST 36          // vtc chunk-blocks per bh (33 used)

typedef __attribute__((ext_vector_type(8))) short short8;
typedef __attribute__((ext_vector_type(4))) float f32x4;

__device__ inline unsigned short bf16u(float x) {
    __hip_bfloat16 t = __float2bfloat16(x);
    return *(unsigned short*)&t;
}
__device__ inline void load_lds16(const void* g, void* l) {
    __builtin_amdgcn_global_load_lds(
        (const __attribute__((address_space(1))) unsigned int*)g,
        (__attribute__((address_space(3))) unsigned int*)l, 16, 0, 0);
}

// ---------------------------------------------------------------------------
// Fused prep: blocks 0..31 build the H x 32 x 32 bias table; rest cast to bf16.
// ---------------------------------------------------------------------------
#define PER_ ((size_t)B_ * H_ * N_ * HD_)      // 4,198,400
#define SZ_QKVW (3 * C_ * C_)
#define SZ_PRJW (C_ * C_)
#define CAST_BLKS ((4198400 + 786432 + 262144) / 4 / 256)   // 5124

__global__ void prep_kernel(const float* __restrict__ x,
                            const float* __restrict__ qkv_w,
                            const float* __restrict__ proj_w,
                            const float* __restrict__ wg_w,
                            const float* __restrict__ wg_b,
                            unsigned short* __restrict__ xb,
                            unsigned short* __restrict__ wqkvb,
                            unsigned short* __restrict__ wprjb,
                            float* __restrict__ tab) {
    int blk = blockIdx.x;
    int tid = threadIdx.x;
    if (blk < 32) {
        int idx = blk * 256 + tid;
        int h = idx >> 10;
        int a = (idx >> 5) & 31;
        int b = idx & 31;
        float dx = logf(fmaxf((float)a * (1.0f / 33.0f), 0.001f));
        float dy = logf(fmaxf((float)b * (1.0f / 33.0f), 0.001f));
        const float* w = wg_w + h * 64;
        float acc = wg_b[h];
#pragma unroll
        for (int k = 0; k < 8; k++) {
            float f = powf(1000.0f, -(float)k * 0.125f);
            float X = 100.0f * dx * f;
            float Y = 100.0f * dy * f;
            acc += w[k]      * sinf(X);
            acc += w[8 + k]  * sinf(Y);
            acc += w[32 + k] * cosf(X);
            acc += w[40 + k] * cosf(Y);
            acc += w[48 + k] + w[56 + k];
        }
        tab[idx] = logf(fmaxf(fmaxf(acc, 0.0f), 1e-6f));
        return;
    }
    long i4 = ((long)(blk - 32) * 256 + tid) * 4;
    const float* src;
    unsigned short* dst;
    long off;
    if (i4 < (long)PER_)                    { src = x;      dst = xb;    off = i4; }
    else if (i4 < (long)PER_ + SZ_QKVW)     { src = qkv_w;  dst = wqkvb; off = i4 - PER_; }
    else                                    { src = proj_w; dst = wprjb; off = i4 - PER_ - SZ_QKVW; }
    float4 v = *(const float4*)(src + off);
    ushort4 p;
    p.x = bf16u(v.x); p.y = bf16u(v.y); p.z = bf16u(v.z); p.w = bf16u(v.w);
    *(ushort4*)(dst + off) = p;
}

// ---------------------------------------------------------------------------
// MFMA GEMM, 128x128 tile, BK=32, 4 waves, unified swapped-operand MFMA
// (lane = token, reg = feature). q/k: ushort4 row stores. v: key-contiguous
// stores in 16-lane runs to vtc [bh][ch(VST)][dim][32].
// ---------------------------------------------------------------------------
#define GK 512

__global__ __launch_bounds__(256) void gemm_qkv_mfma(
        const unsigned short* __restrict__ A, const unsigned short* __restrict__ W,
        unsigned short* __restrict__ qb, unsigned short* __restrict__ kb,
        unsigned short* __restrict__ vtc) {
    __shared__ __align__(16) unsigned short As[128 * 32];
    __shared__ __align__(16) unsigned short Bs[128 * 32];
    int tid = threadIdx.x;
    int w = tid >> 6, lane = tid & 63;
    int quad = lane >> 4, l16 = lane & 15;
    int m0 = blockIdx.y * 128;
    int n0 = blockIdx.x * 128;
    int wr = (w >> 1) * 64, wc = (w & 1) * 64;

    int c0 = tid, c1 = tid + 256;
    int a_r0 = min(m0 + (c0 >> 2), M_ - 1), a_c0 = (c0 & 3) * 8;
    int a_r1 = min(m0 + (c1 >> 2), M_ - 1), a_c1 = (c1 & 3) * 8;
    int b_r0 = n0 + (c0 >> 2), b_r1 = n0 + (c1 >> 2);

    int which = n0 >> 9;                       // 0=q 1=k 2=v
    int h = ((n0 + wc) >> 6) & 7;

    f32x4 acc[4][4];
    const f32x4 zero4 = {0.f, 0.f, 0.f, 0.f};
#pragma unroll
    for (int mi = 0; mi < 4; mi++)
#pragma unroll
        for (int ni = 0; ni < 4; ni++) acc[mi][ni] = zero4;

    for (int k0 = 0; k0 < GK; k0 += 32) {
        __syncthreads();
        load_lds16(A + (size_t)a_r0 * GK + k0 + a_c0, &As[w * 512]);
        load_lds16(A + (size_t)a_r1 * GK + k0 + a_c1, &As[2048 + w * 512]);
        load_lds16(W + (size_t)b_r0 * GK + k0 + a_c0, &Bs[w * 512]);
        load_lds16(W + (size_t)b_r1 * GK + k0 + a_c1, &Bs[2048 + w * 512]);
        __syncthreads();
        short8 af[4], bf[4];
#pragma unroll
        for (int mi = 0; mi < 4; mi++)
            af[mi] = *(const short8*)&As[(wr + mi * 16 + l16) * 32 + quad * 8];
#pragma unroll
        for (int ni = 0; ni < 4; ni++)
            bf[ni] = *(const short8*)&Bs[(wc + ni * 16 + l16) * 32 + quad * 8];
#pragma unroll
        for (int mi = 0; mi < 4; mi++)
#pragma unroll
            for (int ni = 0; ni < 4; ni++)
                acc[mi][ni] = __builtin_amdgcn_mfma_f32_16x16x32_bf16(
                    bf[ni], af[mi], acc[mi][ni], 0, 0, 0);
    }

    if (which < 2) {
        unsigned short* dst = (which == 0) ? qb : kb;
        float sc = (which == 0) ? 0.125f : 1.0f;
#pragma unroll
        for (int mi = 0; mi < 4; mi++) {
            int m = m0 + wr + mi * 16 + l16;
            if (m < M_) {
                int bb = m / N_;
                int i  = m - bb * N_;
                unsigned short* row = dst + ((size_t)(bb * H_ + h) * N_ + i) * HD_;
#pragma unroll
                for (int ni = 0; ni < 4; ni++) {
                    ushort4 pk;
                    pk.x = bf16u(acc[mi][ni][0] * sc);
                    pk.y = bf16u(acc[mi][ni][1] * sc);
                    pk.z = bf16u(acc[mi][ni][2] * sc);
                    pk.w = bf16u(acc[mi][ni][3] * sc);
                    *(ushort4*)(row + ni * 16 + quad * 4) = pk;
                }
            }
        }
    } else {
#pragma unroll
        for (int mi = 0; mi < 4; mi++) {
            int m = m0 + wr + mi * 16 + l16;
            if (m < M_) {
                int bb = m / N_;
                int i  = m - bb * N_;
                int ch = i >> 5, key = i & 31;
                unsigned short* base = vtc + ((size_t)(bb * H_ + h) * VST + ch) * VCS + key;
#pragma unroll
                for (int ni = 0; ni < 4; ni++)
#pragma unroll
                    for (int reg = 0; reg < 4; reg++)
                        base[(ni * 16 + quad * 4 + reg) * 32] = bf16u(acc[mi][ni][reg]);
            }
        }
    }
}

__global__ __launch_bounds__(256) void gemm_proj_mfma(
        const unsigned short* __restrict__ A, const unsigned short* __restrict__ W,
        const float* __restrict__ bias, float* __restrict__ out) {
    __shared__ __align__(16) unsigned short As[128 * 32];
    __shared__ __align__(16) unsigned short Bs[128 * 32];
    int tid = threadIdx.x;
    int w = tid >> 6, lane = tid & 63;
    int quad = lane >> 4, l16 = lane & 15;
    int m0 = blockIdx.y * 128;
    int n0 = blockIdx.x * 128;
    int wr = (w >> 1) * 64, wc = (w & 1) * 64;

    int c0 = tid, c1 = tid + 256;
    int a_r0 = min(m0 + (c0 >> 2), M_ - 1), a_c0 = (c0 & 3) * 8;
    int a_r1 = min(m0 + (c1 >> 2), M_ - 1), a_c1 = (c1 & 3) * 8;
    int b_r0 = n0 + (c0 >> 2), b_r1 = n0 + (c1 >> 2);

    f32x4 acc[4][4];
    const f32x4 zero4 = {0.f, 0.f, 0.f, 0.f};
#pragma unroll
    for (int mi = 0; mi < 4; mi++)
#pragma unroll
        for (int ni = 0; ni < 4; ni++) acc[mi][ni] = zero4;

    for (int k0 = 0; k0 < GK; k0 += 32) {
        __syncthreads();
        load_lds16(A + (size_t)a_r0 * GK + k0 + a_c0, &As[w * 512]);
        load_lds16(A + (size_t)a_r1 * GK + k0 + a_c1, &As[2048 + w * 512]);
        load_lds16(W + (size_t)b_r0 * GK + k0 + a_c0, &Bs[w * 512]);
        load_lds16(W + (size_t)b_r1 * GK + k0 + a_c1, &Bs[2048 + w * 512]);
        __syncthreads();
        short8 af[4], bf[4];
#pragma unroll
        for (int mi = 0; mi < 4; mi++)
            af[mi] = *(const short8*)&As[(wr + mi * 16 + l16) * 32 + quad * 8];
#pragma unroll
        for (int ni = 0; ni < 4; ni++)
            bf[ni] = *(const short8*)&Bs[(wc + ni * 16 + l16) * 32 + quad * 8];
#pragma unroll
        for (int mi = 0; mi < 4; mi++)
#pragma unroll
            for (int ni = 0; ni < 4; ni++)
                acc[mi][ni] = __builtin_amdgcn_mfma_f32_16x16x32_bf16(
                    af[mi], bf[ni], acc[mi][ni], 0, 0, 0);
    }

    float bvals[4];
#pragma unroll
    for (int ni = 0; ni < 4; ni++) bvals[ni] = bias[n0 + wc + ni * 16 + l16];
#pragma unroll
    for (int mi = 0; mi < 4; mi++)
#pragma unroll
        for (int reg = 0; reg < 4; reg++) {
            int m = m0 + wr + mi * 16 + quad * 4 + reg;
            if (m < M_) {
                float* row = out + (size_t)m * C_ + n0 + wc;
#pragma unroll
                for (int ni = 0; ni < 4; ni++)
                    row[ni * 16 + l16] = acc[mi][ni][reg] + bvals[ni];
            }
        }
}

// ---------------------------------------------------------------------------
// FUSED attention v5: 96-KEY TILES for LDS headroom. R15/16 used 80 KB/block
// = exactly the whole 160 KB pool for 2 blocks -> occupancy counters say the
// 2nd block never co-resided. 96-key tiles (1056 = 11 x 96 exactly):
// Ks 2x12K + Vs 2x12K + Pw 11.25K + tabs 4.3K = 65 KB -> 2 blocks/CU with
// 33 KB slack. Plain V layout (R16's XOR swizzle fixed conflicts but cost
// time - reverted). Staging: waves 0-5 stage K (2 rounds), waves 6-8 stage
// V (4 rounds), all lane-linear verbatim. One barrier per tile (11 tiles).
// ---------------------------------------------------------------------------
#define RT_ 144   // rows per tile (9 waves x 16)

__global__ __launch_bounds__(576) void attn_fused(
        const unsigned short* __restrict__ qg,
        const unsigned short* __restrict__ kg,
        const unsigned short* __restrict__ vtc,
        const float* __restrict__ tab,
        unsigned short* __restrict__ ob) {
    // Ks chunk ch = ct*128 + oct*16 + k16 holds K[key=t*96+ct*16+k16][oct*8..+8]
    // Vs: 3 ks-blocks of 256 chunks, chunk = dim*4 + koct (plain vtc layout)
    __shared__ __align__(16) unsigned short Ks[2][6144];   // 24 KB
    __shared__ __align__(16) unsigned short Vs[2][6144];   // 24 KB
    __shared__ __align__(16) unsigned short Pw[9][16 * 40];// 11.25 KB
    __shared__ float tabs[1089];                           // 4.3 KB (33x33)

    int tid = threadIdx.x;
    int w = tid >> 6, lane = tid & 63;
    int quad = lane >> 4, l16 = lane & 15;

    int lin = blockIdx.x;
    int xcd = lin & 7;
    int u = lin >> 3;
    int bhi = u & 7;
    int mt = u >> 3;                 // 0..7
    int bh = xcd * 8 + bhi;
    int b = bh >> 3, h = bh & 7;

    const unsigned short* qp = qg + (size_t)bh * N_ * HD_;
    const unsigned short* kp = kg + (size_t)bh * N_ * HD_;
    const unsigned short* vp = vtc + (size_t)bh * VST * VCS;

    for (int i = tid; i < 1024; i += 576)
        tabs[(i >> 5) * 33 + (i & 31)] = tab[h * 1024 + i];

    // Q fragments: wave owns rows mt*144 + w*16 + l16 (A-layout, clamped)
    short8 qf[2];
    {
        int row = min(mt * RT_ + w * 16 + l16, N_ - 1);
        qf[0] = *(const short8*)(qp + (size_t)row * HD_ + quad * 8);
        qf[1] = *(const short8*)(qp + (size_t)row * HD_ + 32 + quad * 8);
    }

    // row-side bias constants (C-layout rows: quad*4+reg)
    int rpx[4], rpy[4];
    bool rz[4];
#pragma unroll
    for (int reg = 0; reg < 4; reg++) {
        int r = mt * RT_ + w * 16 + quad * 4 + reg;
        int ri = min(max(r - 1, 0), N_ - 2);
        rpx[reg] = ri >> 5;
        rpy[reg] = ri & 31;
        rz[reg] = (r == 0);
    }

    f32x4 o_acc[4], l_acc;
    const f32x4 zero4 = {0.f, 0.f, 0.f, 0.f};
#pragma unroll
    for (int g2 = 0; g2 < 4; g2++) o_acc[g2] = zero4;
    l_acc = zero4;
    short8 ones;
    {
        short one_bf = (short)0x3F80;
#pragma unroll
        for (int j = 0; j < 8; j++) ones[j] = one_bf;
    }

    // staging: waves 0-5 -> K (768 chunks, 2 rounds of 6 waves);
    //          waves 6-8 -> V (768 chunks, 4 rounds of 3 waves). Lane-linear.
    auto stage = [&](int t, int buf) {
        if (w < 6) {
#pragma unroll
            for (int r2 = 0; r2 < 2; r2++) {
                int cb = (r2 * 6 + w) * 64;      // base chunk
                int ch = cb + lane;
                int ct = ch >> 7, rem = ch & 127;
                int oct = rem >> 4, k16 = rem & 15;
                int key = min(t * 96 + ct * 16 + k16, N_ - 1);
                load_lds16(kp + (size_t)key * HD_ + oct * 8, &Ks[buf][cb * 8]);
            }
        } else {
            int wv = w - 6;
#pragma unroll
            for (int r2 = 0; r2 < 4; r2++) {
                int cb = (r2 * 3 + wv) * 64;
                load_lds16(vp + (size_t)t * 3 * VCS + (size_t)(cb + lane) * 8,
                           &Vs[buf][cb * 8]);
            }
        }
    };

    stage(0, 0);

#pragma unroll 1
    for (int t = 0; t < 11; t++) {
        int buf = t & 1;
        __syncthreads();                  // Ks/Vs[buf] ready (vmcnt drained)
        if (t < 10) stage(t + 1, buf ^ 1);

        // ---- QK: S[16 rows][96 cols] = 6 ct tiles ----
        f32x4 s[6];
#pragma unroll
        for (int ct = 0; ct < 6; ct++) {
            short8 b0 = *(const short8*)&Ks[buf][(ct * 128 + quad * 16 + l16) * 8];
            short8 b1 = *(const short8*)&Ks[buf][(ct * 128 + (4 + quad) * 16 + l16) * 8];
            s[ct] = __builtin_amdgcn_mfma_f32_16x16x32_bf16(qf[0], b0, zero4, 0, 0, 0);
            s[ct] = __builtin_amdgcn_mfma_f32_16x16x32_bf16(qf[1], b1, s[ct], 0, 0, 0);
        }

        // ---- 3 steps of 32 cols: exp+pack (per-wave LDS), then PV ----
#pragma unroll
        for (int ks = 0; ks < 3; ks++) {
#pragma unroll
            for (int ctl = 0; ctl < 2; ctl++) {
                int ct = ks * 2 + ctl;
                int col = t * 96 + ct * 16 + l16;
                int ji = col - 1;
                int cx = ji >> 5, cy = ji & 31;
                bool cz = (col == 0), co = (col >= N_);
#pragma unroll
                for (int reg = 0; reg < 4; reg++) {
                    float bia = 0.f;
                    if (!rz[reg] && !cz) {
                        int da = __sad(rpx[reg], cx, 0u);
                        int db = __sad(rpy[reg], cy, 0u);
                        bia = tabs[da * 33 + db];
                    }
                    float p = co ? 0.f : __expf(s[ct][reg] + bia);
                    Pw[w][(quad * 4 + reg) * 40 + ctl * 16 + l16] = bf16u(p);
                }
            }
            // PV for this 32-key step; V from LDS (plain layout)
            short8 pf = *(const short8*)&Pw[w][l16 * 40 + quad * 8];
            const unsigned short* vcp = &Vs[buf][ks * 2048 + quad * 8];
#pragma unroll
            for (int g2 = 0; g2 < 4; g2++) {
                short8 vf = *(const short8*)(vcp + (g2 * 16 + l16) * 32);
                o_acc[g2] = __builtin_amdgcn_mfma_f32_16x16x32_bf16(
                    pf, vf, o_acc[g2], 0, 0, 0);
            }
            l_acc = __builtin_amdgcn_mfma_f32_16x16x32_bf16(pf, ones, l_acc, 0, 0, 0);
        }
    }

    // ---- epilogue: o/l -> ob bf16 (C-layout rows; pad rows skip store) ----
#pragma unroll
    for (int reg = 0; reg < 4; reg++) {
        int r = mt * RT_ + w * 16 + quad * 4 + reg;
        if (r < N_) {
            float inv = 1.0f / l_acc[reg];
            unsigned short* orow = ob + ((size_t)b * N_ + r) * C_ + h * HD_ + l16;
#pragma unroll
            for (int g2 = 0; g2 < 4; g2++)
                orow[g2 * 16] = bf16u(o_acc[g2][reg] * inv);
        }
    }
}

// ---------------------------------------------------------------------------
extern "C" void kernel_launch(void* const* d_in, const int* in_sizes, int n_in,
                              void* d_out, int out_size, void* d_ws, size_t ws_size,
                              hipStream_t stream) {
    const float* x      = (const float*)d_in[0];
    const float* qkv_w  = (const float*)d_in[1];
    const float* proj_w = (const float*)d_in[2];
    const float* proj_b = (const float*)d_in[3];
    const float* wg_w   = (const float*)d_in[4];
    const float* wg_b   = (const float*)d_in[5];
    float* out = (float*)d_out;

    const size_t per = PER_;
    char* ws = (char*)d_ws;
    float* tab            = (float*)ws;                           // 32 KB
    unsigned short* xb    = (unsigned short*)(ws + (32 << 10));   // 8,396,800 B
    unsigned short* wqkvb = xb + per;                             // 1,572,864 B
    unsigned short* wprjb = wqkvb + (size_t)SZ_QKVW;              //   524,288 B
    unsigned short* qb    = wprjb + (size_t)SZ_PRJW;              // 8,396,800 B
    unsigned short* kb    = qb + per;                             // 8,396,800 B
    unsigned short* vtc   = kb + per;                             // 9,437,184 B
    unsigned short* ob    = vtc + (size_t)64 * VST * VCS;         // 8,396,800 B

    prep_kernel<<<32 + CAST_BLKS, 256, 0, stream>>>(x, qkv_w, proj_w, wg_w, wg_b,
                                                    xb, wqkvb, wprjb, tab);
    gemm_qkv_mfma<<<dim3(12, 65), 256, 0, stream>>>(xb, wqkvb, qb, kb, vtc);
    attn_fused<<<8 * 8 * 8, 576, 0, stream>>>(qb, kb, vtc, tab, ob);
    gemm_proj_mfma<<<dim3(4, 65), 256, 0, stream>>>(ob, wprjb, proj_b, out);
}